// Round 7
// baseline (816.410 us; speedup 1.0000x reference)
//
#include <hip/hip_runtime.h>
#include <cstdint>
#include <cstddef>

// ===========================================================================
// FP16 MFMA pipeline (R14).
// R14 changes vs R13:
//  (1) NEW conv_mfma2 for all 16x16-tile conv layers: 128-thread blocks
//      (2 waves), MT=8 x NT=4 per wave (acc[8][4]=128 VGPR). Rationale:
//      R9-R13 showed dur ~183us invariant to occupancy (32->56%) — the
//      kernel is WEIGHT-L2-BANDWIDTH-bound: each MFMA consumed 1KB of
//      B-fragment from L2 reused only MT=4 times; per-CU L2 share (~56B/cy)
//      caps MFMA duty at ~27% regardless of wave count. MT=8 halves weight
//      traffic per MFMA (288->144KB/block) -> duty ceiling ~53%. 32-MFMA
//      trains per phase also cover latency with just 2 waves/SIMD.
//      IC-split staging retained (25.9KB LDS). launch_bounds(128,2):
//      VGPR cap 256 (acc cannot spill — R12 lesson).
//  (2) Old conv_mfma kept only for the 8x8 L6 layer.
// ===========================================================================

typedef _Float16 f16x8 __attribute__((ext_vector_type(8)));
typedef __attribute__((ext_vector_type(4))) float f32x4;

#define WL 36864  // fp16 elems per transformed conv layer: 9 taps * 8 * 512

// ---------------------------------------------------------------------------
// Conv weight transform: cw_rest [5][64][64][3][3] ->
//   wbuf5 [5][tap9][cc2][nt4][64][8] fp16 ; cw1 -> w1buf [nt4][64][8] (K=27 pad 32)
// ---------------------------------------------------------------------------
__global__ __launch_bounds__(256)
void wtransform(const float* __restrict__ cwr, const float* __restrict__ cw1,
                _Float16* __restrict__ wbuf5, _Float16* __restrict__ w1buf) {
  int i = blockIdx.x * 256 + threadIdx.x;
  if (i < 184320) {
    int layer = i / 36864; int rem = i - layer * 36864;
    int tap = rem / 4096;  int r2 = rem - tap * 4096;
    int cc = r2 / 2048;    int r3 = r2 - cc * 2048;
    int nt = r3 / 512;     int r4 = r3 - nt * 512;
    int lane = r4 / 8;     int j = r4 - lane * 8;
    int ic = cc * 32 + (lane >> 4) * 8 + j;
    int oc = nt * 16 + (lane & 15);
    float w = cwr[(((size_t)layer * 64 + oc) * 64 + ic) * 9 + tap];
    wbuf5[(size_t)layer * 36864 + tap * 4096 + (cc * 4 + nt) * 512 + lane * 8 + j] =
        (_Float16)w;
  } else if (i < 184320 + 2048) {
    int e = i - 184320;
    int nt = e / 512; int r4 = e - nt * 512;
    int lane = r4 / 8; int j = r4 - lane * 8;
    int k = (lane >> 4) * 8 + j;
    float w = 0.f;
    if (k < 27) {
      int tap = k / 3, ic = k - tap * 3;
      int oc = nt * 16 + (lane & 15);
      w = cw1[((size_t)oc * 3 + ic) * 9 + tap];
    }
    w1buf[nt * 512 + lane * 8 + j] = (_Float16)w;
  }
}

// ---------------------------------------------------------------------------
// Lin weight transform: W [K,1024] -> frag [K/32][nt64][64][8] fp16.
// ---------------------------------------------------------------------------
__global__ __launch_bounds__(256)
void wtransform_lin(const float* __restrict__ w, _Float16* __restrict__ frag,
                    int KS) {
  int i = blockIdx.x * 256 + threadIdx.x;
  int total = KS * 64 * 512;
  if (i >= total) return;
  int ks = i / (64 * 512); int rem = i - ks * (64 * 512);
  int nt = rem / 512;      int r = rem - nt * 512;
  int lane = r / 8;        int j = r - lane * 8;
  int k = ks * 32 + (lane >> 4) * 8 + j;
  int n = nt * 16 + (lane & 15);
  frag[((size_t)ks * 64 + nt) * 512 + lane * 8 + j] = (_Float16)w[(size_t)k * 1024 + n];
}

// ---------------------------------------------------------------------------
// FP16 MFMA gemm: out[m,n] = sum_k A[m,k] W[k,n] + bias[n]; A fp32 rows.
// 32-col blocks, grid (32, ceil(M/16)) = 288 blocks.
// ---------------------------------------------------------------------------
template<int KTOT>
__global__ __launch_bounds__(256)
void gemm_mfma(const float* __restrict__ A1, const float* __restrict__ A2,
               const _Float16* __restrict__ frag,
               const float* __restrict__ bias, float* __restrict__ out, int M) {
  __shared__ f32x4 s_red[4][2][64];  // 8KB
  const int tid = threadIdx.x;
  const int wave = tid >> 6, lane = tid & 63;
  const int q = lane >> 4, ml = lane & 15;
  const int m0 = blockIdx.y * 16;
  const int nb = blockIdx.x;           // 32-col block
  int row = m0 + ml; if (row >= M) row = M - 1;

  f32x4 acc[2];
#pragma unroll
  for (int nt = 0; nt < 2; ++nt) acc[nt] = (f32x4){0.f, 0.f, 0.f, 0.f};

  constexpr int KSW = KTOT / 128;
  const int ksBase = wave * KSW;
#pragma unroll 2
  for (int s = 0; s < KSW; ++s) {
    int ks = ksBase + s;
    int k0 = ks * 32 + q * 8;
    const float* ap;
    if constexpr (KTOT == 2048) {
      ap = (k0 >= 1024) ? (A2 + (size_t)row * 1024 + (k0 - 1024))
                        : (A1 + (size_t)row * 1024 + k0);
    } else {
      ap = A1 + (size_t)row * 1024 + k0;
    }
    float4 va = *(const float4*)ap;
    float4 vb = *(const float4*)(ap + 4);
    f16x8 av;
    av[0] = (_Float16)va.x; av[1] = (_Float16)va.y;
    av[2] = (_Float16)va.z; av[3] = (_Float16)va.w;
    av[4] = (_Float16)vb.x; av[5] = (_Float16)vb.y;
    av[6] = (_Float16)vb.z; av[7] = (_Float16)vb.w;
    const _Float16* fb = frag + ((size_t)ks * 64 + nb * 2) * 512 + lane * 8;
#pragma unroll
    for (int nt = 0; nt < 2; ++nt) {
      f16x8 bv = *(const f16x8*)(fb + nt * 512);
      acc[nt] = __builtin_amdgcn_mfma_f32_16x16x32_f16(av, bv, acc[nt], 0, 0, 0);
    }
  }
#pragma unroll
  for (int nt = 0; nt < 2; ++nt) s_red[wave][nt][lane] = acc[nt];
  __syncthreads();
  if (wave < 2) {
    int nt = wave;
    f32x4 sum = s_red[0][nt][lane];
#pragma unroll
    for (int w2 = 1; w2 < 4; ++w2) {
      f32x4 p = s_red[w2][nt][lane];
      sum[0] += p[0]; sum[1] += p[1]; sum[2] += p[2]; sum[3] += p[3];
    }
    int n = nb * 32 + nt * 16 + ml;
    float bv = bias[n];
#pragma unroll
    for (int r = 0; r < 4; ++r) {
      int m = m0 + q * 4 + r;
      if (m < M) out[(size_t)m * 1024 + n] = sum[r] + bv;
    }
  }
}

// ---------------------------------------------------------------------------
// conv3x3(SAME)+bias+relu+maxpool2, IC=OC=64. R14 main conv kernel:
// 128 threads = 2 waves; wave covers 128 positions (MT=8) x all 64 OCs
// (NT=4). 16x16 tile, IC-split staging (stride 40 hw, 25.9KB LDS).
// Per (tap,cc): 4 weight frags serve 32 MFMAs (2x weight L2 amortization
// vs the old 4-wave kernel — the measured bottleneck).
// ---------------------------------------------------------------------------
template<bool FP32OUT>
__global__ __launch_bounds__(128, 2)
void conv_mfma2(const _Float16* __restrict__ act_in,
                void* __restrict__ act_out,
                const _Float16* __restrict__ wbuf,   // [9][cc2][nt4][64][8]
                const float* __restrict__ bias,
                int IH, int IW) {
  constexpr int PX = 18, PY = 18;
  __shared__ __align__(16) _Float16 s_patch[PY * PX * 40];

  const int tid = threadIdx.x;
  const int wave = tid >> 6, lane = tid & 63;
  const int q = lane >> 4, ml = lane & 15;
  const int x0 = blockIdx.x * 16, y0 = blockIdx.y * 16;
  const int img = blockIdx.z;

  f32x4 acc[8][4];
#pragma unroll
  for (int mt = 0; mt < 8; ++mt)
#pragma unroll
    for (int nt = 0; nt < 4; ++nt)
      acc[mt][nt] = (f32x4){0.f, 0.f, 0.f, 0.f};

#pragma unroll 1
  for (int cc = 0; cc < 2; ++cc) {
    if (cc) __syncthreads();   // all waves done reading phase-0 data

    // stage 32-channel half: 4 x 16B per position, coalesced
    for (int u = tid; u < PY * PX * 4; u += 128) {
      int pos = u >> 2, sub = u & 3;
      int py = pos / PX, px = pos - py * PX;
      int gy = y0 - 1 + py, gx = x0 - 1 + px;
      uint4 v = {0u, 0u, 0u, 0u};
      if ((unsigned)gy < (unsigned)IH && (unsigned)gx < (unsigned)IW)
        v = *(const uint4*)(act_in +
              (((size_t)img * IH + gy) * IW + gx) * 64 + cc * 32 + sub * 8);
      *(uint4*)(s_patch + pos * 40 + sub * 8) = v;
    }

    // prefetch tap 0 weights for this half (4 fragments)
    const _Float16* wl = wbuf + cc * 2048 + lane * 8;
    f16x8 bw[4], bn[4];
#pragma unroll
    for (int f = 0; f < 4; ++f) bw[f] = *(const f16x8*)(wl + f * 512);

    __syncthreads();

#pragma unroll 1
    for (int tap = 0; tap < 9; ++tap) {
      if (tap < 8) {
        const _Float16* np = wl + (tap + 1) * 4096;
#pragma unroll
        for (int f = 0; f < 4; ++f) bn[f] = *(const f16x8*)(np + f * 512);
      }
      const int dy = tap / 3, dx = tap - dy * 3;
#pragma unroll
      for (int mt = 0; mt < 8; ++mt) {
        const _Float16* ap =
            s_patch + ((wave * 8 + mt + dy) * PX + (ml + dx)) * 40 + q * 8;
        f16x8 av = *(const f16x8*)ap;
#pragma unroll
        for (int nt = 0; nt < 4; ++nt)
          acc[mt][nt] = __builtin_amdgcn_mfma_f32_16x16x32_f16(av, bw[nt],
                                                               acc[mt][nt], 0, 0, 0);
      }
#pragma unroll
      for (int f = 0; f < 4; ++f) bw[f] = bn[f];
    }
  }

  // ---- in-register bias+relu+2x2 maxpool + direct store ----
  const int OH = IH >> 1, OW = IW >> 1;
#pragma unroll
  for (int nt = 0; nt < 4; ++nt) {
    int oc = nt * 16 + ml;
    float bvs = bias[oc];
#pragma unroll
    for (int mh = 0; mh < 4; ++mh)
#pragma unroll
      for (int rh = 0; rh < 2; ++rh) {
        float a0 = fmaxf(acc[2 * mh][nt][2 * rh] + bvs, 0.f);
        float a1 = fmaxf(acc[2 * mh][nt][2 * rh + 1] + bvs, 0.f);
        float a2 = fmaxf(acc[2 * mh + 1][nt][2 * rh] + bvs, 0.f);
        float a3 = fmaxf(acc[2 * mh + 1][nt][2 * rh + 1] + bvs, 0.f);
        float m = fmaxf(fmaxf(a0, a1), fmaxf(a2, a3));
        int gy = (y0 >> 1) + wave * 4 + mh;
        int gx = (x0 >> 1) + q * 2 + rh;
        if (FP32OUT)
          ((float*)act_out)[(((size_t)img * 64 + oc) * OH + gy) * OW + gx] = m;
        else
          ((_Float16*)act_out)[(((size_t)img * OH + gy) * OW + gx) * 64 + oc] =
              (_Float16)m;
      }
  }
}

// ---------------------------------------------------------------------------
// Old 256-thread conv kernel — retained only for the 8x8 L6 layer.
// IC-split staging (stride 40), R13 form.
// ---------------------------------------------------------------------------
template<int TCX, int TCY, bool FP32OUT>
__global__ __launch_bounds__(256, 4)
void conv_mfma(const _Float16* __restrict__ act_in,
               void* __restrict__ act_out,
               const _Float16* __restrict__ wbuf,   // [9][cc2][nt4][64][8]
               const float* __restrict__ bias,
               int IH, int IW) {
  constexpr int PX = TCX + 2, PY = TCY + 2;
  constexpr int MT = (TCX * TCY) / 64;
  __shared__ __align__(16) _Float16 s_patch[PY * PX * 40];

  const int tid = threadIdx.x;
  const int wave = tid >> 6, lane = tid & 63;
  const int q = lane >> 4, ml = lane & 15;
  const int x0 = blockIdx.x * TCX, y0 = blockIdx.y * TCY;
  const int img = blockIdx.z;

  f32x4 acc[MT][4];
#pragma unroll
  for (int mt = 0; mt < MT; ++mt)
#pragma unroll
    for (int nt = 0; nt < 4; ++nt)
      acc[mt][nt] = (f32x4){0.f, 0.f, 0.f, 0.f};

  int pxv[MT], pyv[MT];
#pragma unroll
  for (int mt = 0; mt < MT; ++mt) {
    int p = (wave * MT + mt) * 16 + ml;
    pxv[mt] = p % TCX;
    pyv[mt] = p / TCX;
  }

#pragma unroll 1
  for (int cc = 0; cc < 2; ++cc) {
    if (cc) __syncthreads();

    for (int u = tid; u < PY * PX * 4; u += 256) {
      int pos = u >> 2, sub = u & 3;
      int py = pos / PX, px = pos - py * PX;
      int gy = y0 - 1 + py, gx = x0 - 1 + px;
      uint4 v = {0u, 0u, 0u, 0u};
      if ((unsigned)gy < (unsigned)IH && (unsigned)gx < (unsigned)IW)
        v = *(const uint4*)(act_in +
              (((size_t)img * IH + gy) * IW + gx) * 64 + cc * 32 + sub * 8);
      *(uint4*)(s_patch + pos * 40 + sub * 8) = v;
    }

    const _Float16* wl = wbuf + cc * 2048 + lane * 8;
    f16x8 bw[4], bn[4];
#pragma unroll
    for (int f = 0; f < 4; ++f) bw[f] = *(const f16x8*)(wl + f * 512);

    __syncthreads();

#pragma unroll 1
    for (int tap = 0; tap < 9; ++tap) {
      if (tap < 8) {
        const _Float16* np = wl + (tap + 1) * 4096;
#pragma unroll
        for (int f = 0; f < 4; ++f) bn[f] = *(const f16x8*)(np + f * 512);
      }
      const int dy = tap / 3, dx = tap - dy * 3;
#pragma unroll
      for (int mt = 0; mt < MT; ++mt) {
        const _Float16* ap =
            s_patch + ((pyv[mt] + dy) * PX + (pxv[mt] + dx)) * 40 + q * 8;
        f16x8 av = *(const f16x8*)ap;
#pragma unroll
        for (int nt = 0; nt < 4; ++nt)
          acc[mt][nt] = __builtin_amdgcn_mfma_f32_16x16x32_f16(av, bw[nt],
                                                               acc[mt][nt], 0, 0, 0);
      }
#pragma unroll
      for (int f = 0; f < 4; ++f) bw[f] = bn[f];
    }
  }

  const int OH = IH >> 1, OW = IW >> 1;
#pragma unroll
  for (int nt = 0; nt < 4; ++nt) {
    int oc = nt * 16 + ml;
    float bvs = bias[oc];
    if constexpr (TCX == 16) {
#pragma unroll
      for (int mh = 0; mh < MT / 2; ++mh)
#pragma unroll
        for (int rh = 0; rh < 2; ++rh) {
          float a0 = fmaxf(acc[2 * mh][nt][2 * rh] + bvs, 0.f);
          float a1 = fmaxf(acc[2 * mh][nt][2 * rh + 1] + bvs, 0.f);
          float a2 = fmaxf(acc[2 * mh + 1][nt][2 * rh] + bvs, 0.f);
          float a3 = fmaxf(acc[2 * mh + 1][nt][2 * rh + 1] + bvs, 0.f);
          float m = fmaxf(fmaxf(a0, a1), fmaxf(a2, a3));
          int gy = (y0 >> 1) + wave * (MT / 2) + mh;
          int gx = (x0 >> 1) + q * 2 + rh;
          if (FP32OUT)
            ((float*)act_out)[(((size_t)img * 64 + oc) * OH + gy) * OW + gx] = m;
          else
            ((_Float16*)act_out)[(((size_t)img * OH + gy) * OW + gx) * 64 + oc] =
                (_Float16)m;
        }
    } else {  // TCX==8, MT==1: y-pool across q>>1 via shfl_xor(32)
      float m01 = fmaxf(fmaxf(acc[0][nt][0] + bvs, 0.f), fmaxf(acc[0][nt][1] + bvs, 0.f));
      float m23 = fmaxf(fmaxf(acc[0][nt][2] + bvs, 0.f), fmaxf(acc[0][nt][3] + bvs, 0.f));
      float p0 = fmaxf(m01, __shfl_xor(m01, 32));
      float p1 = fmaxf(m23, __shfl_xor(m23, 32));
      if ((lane & 32) == 0) {
        int gy = (y0 >> 1) + wave;
        int gx0 = (x0 >> 1) + (q & 1) * 2;
        if (FP32OUT) {
          float* o = (float*)act_out + (((size_t)img * 64 + oc) * OH + gy) * OW + gx0;
          o[0] = p0; o[1] = p1;
        } else {
          _Float16* o = (_Float16*)act_out;
          o[(((size_t)img * OH + gy) * OW + gx0) * 64 + oc] = (_Float16)p0;
          o[(((size_t)img * OH + gy) * OW + gx0 + 1) * 64 + oc] = (_Float16)p1;
        }
      }
    }
  }
}

// ---------------------------------------------------------------------------
// Layer 1: IC=3, K=27 (pad 32), planar fp32 input. Tile 16x16 -> pooled 8x8.
// No im2col LDS buffer. Halo staged as fp16 [3][18][18]; each lane's 8
// im2col offsets are loop-invariant (computed once); A-fragments built with
// 8 ds_read_u16 per row-group t. k>=27 -> zeroed LDS pad (uniform reads).
// ---------------------------------------------------------------------------
__global__ __launch_bounds__(256, 4)
void conv_l1(const float* __restrict__ in, _Float16* __restrict__ act_out,
             const _Float16* __restrict__ w1buf, const float* __restrict__ bias) {
  __shared__ __align__(16) _Float16 s_rawh[1280];  // [3][18][18]=972 + zero pad

  const int tid = threadIdx.x;
  const int wave = tid >> 6, lane = tid & 63;
  const int q = lane >> 4, ml = lane & 15;
  const int x0 = blockIdx.x * 16, y0 = blockIdx.y * 16;
  const int img = blockIdx.z;

  // zero pad region [972, 1280) absorbs k>=27 fragment reads
  if (tid < 308) s_rawh[972 + tid] = (_Float16)0.f;
  for (int i = tid; i < 972; i += 256) {
    int ic = i / 324, rem = i - ic * 324;
    int yy = rem / 18, xx = rem - yy * 18;
    int gy = y0 - 1 + yy, gx = x0 - 1 + xx;
    float v = 0.f;
    if ((unsigned)gy < 256u && (unsigned)gx < 256u)
      v = in[((size_t)img * 3 + ic) * 65536 + gy * 256 + gx];
    s_rawh[i] = (_Float16)v;
  }

  // per-lane loop-invariant im2col offsets (halfword units)
  int offs[8];
#pragma unroll
  for (int j = 0; j < 8; ++j) {
    int k = q * 8 + j;
    int tap = k / 3, ic = k - tap * 3;
    int ddy = tap / 3, ddx = tap - ddy * 3;
    offs[j] = (k < 27) ? (ic * 324 + ddy * 18 + ddx + ml) : 972;
  }

  f16x8 bv[4];
#pragma unroll
  for (int nt = 0; nt < 4; ++nt)
    bv[nt] = *(const f16x8*)(w1buf + nt * 512 + lane * 8);

  __syncthreads();

  f32x4 acc[4][4];
#pragma unroll
  for (int t4 = 0; t4 < 4; ++t4)
#pragma unroll
    for (int nt = 0; nt < 4; ++nt)
      acc[t4][nt] = (f32x4){0.f, 0.f, 0.f, 0.f};

#pragma unroll
  for (int t4 = 0; t4 < 4; ++t4) {
    const int tb = (wave * 4 + t4) * 18;   // t = y row within 16x16 tile
    f16x8 av;
#pragma unroll
    for (int j = 0; j < 8; ++j) av[j] = s_rawh[offs[j] + tb];
#pragma unroll
    for (int nt = 0; nt < 4; ++nt)
      acc[t4][nt] = __builtin_amdgcn_mfma_f32_16x16x32_f16(av, bv[nt], acc[t4][nt], 0, 0, 0);
  }

#pragma unroll
  for (int nt = 0; nt < 4; ++nt) {
    int oc = nt * 16 + ml;
    float bvs = bias[oc];
#pragma unroll
    for (int mh = 0; mh < 2; ++mh)
#pragma unroll
      for (int rh = 0; rh < 2; ++rh) {
        float a0 = fmaxf(acc[2 * mh][nt][2 * rh] + bvs, 0.f);
        float a1 = fmaxf(acc[2 * mh][nt][2 * rh + 1] + bvs, 0.f);
        float a2 = fmaxf(acc[2 * mh + 1][nt][2 * rh] + bvs, 0.f);
        float a3 = fmaxf(acc[2 * mh + 1][nt][2 * rh + 1] + bvs, 0.f);
        float m = fmaxf(fmaxf(a0, a1), fmaxf(a2, a3));
        int gy = blockIdx.y * 8 + wave * 2 + mh;
        int gx = blockIdx.x * 8 + q * 2 + rh;
        act_out[(((size_t)img * 128 + gy) * 128 + gx) * 64 + oc] = (_Float16)m;
      }
  }
}

// ---------------------------------------------------------------------------
// Graph aggregation (two-phase) + metric head (unchanged).
// ---------------------------------------------------------------------------
__global__ __launch_bounds__(256)
void edge_agg_mul(const float* __restrict__ h, const int* __restrict__ ei,
                  int E, float* __restrict__ out) {
  __shared__ int list[1024];
  __shared__ int cnt;
  const int n = blockIdx.x;
  const int tid = threadIdx.x;
  if (tid == 0) cnt = 0;
  __syncthreads();
  for (int e = tid; e < E; e += 256) {
    if (ei[E + e] == n) {
      int p = atomicAdd(&cnt, 1);
      list[p] = ei[e];
    }
  }
  __syncthreads();
  const int c = cnt;
  float ax = 0.f, ay = 0.f, az = 0.f, aw = 0.f;
#pragma unroll 4
  for (int i = 0; i < c; ++i) {
    const float4 v = ((const float4*)(h + (size_t)list[i] * 1024))[tid];
    ax += v.x; ay += v.y; az += v.z; aw += v.w;
  }
  float inv = 1.f / (float)(c > 0 ? c : 1);
  const float4 hv = ((const float4*)(h + (size_t)n * 1024))[tid];
  float4 o;
  o.x = ax * inv * hv.x; o.y = ay * inv * hv.y;
  o.z = az * inv * hv.z; o.w = aw * inv * hv.w;
  ((float4*)(out + (size_t)n * 1024))[tid] = o;
}

__global__ __launch_bounds__(256)
void rbf_pairs(const float* __restrict__ sx, const float* __restrict__ qx,
               const float* __restrict__ center, float* __restrict__ bpre) {
  int gid = blockIdx.x * 256 + threadIdx.x;
  int wid = gid >> 6;
  int lane = gid & 63;
  if (wid >= 23 * 115) return;
  int qq = wid / 115, s = wid - qq * 115;
  const float* sr = sx + (size_t)s * 1024;
  const float* qr = qx + (size_t)qq * 1024;
  const float* cr = center + (size_t)(s / 5) * 1024;
  float S1 = 0.f, S2 = 0.f, S3 = 0.f;
  for (int d = lane; d < 1024; d += 64) {
    float sv = sr[d], qv = qr[d];
    float df = sv - qv;
    float a = expf(-df * df);
    S1 += a;
    S2 += expf(a);
    float sc = 0.25f * cr[d] + 0.5f * sv;
    float d2 = sc - qv;
    S3 += expf(-d2 * d2);
  }
#pragma unroll
  for (int o = 32; o > 0; o >>= 1) {
    S1 += __shfl_down(S1, o);
    S2 += __shfl_down(S2, o);
    S3 += __shfl_down(S3, o);
  }
  if (lane == 0) bpre[wid] = S3 + S1 - 1024.f * logf(S2);
}

__global__ __launch_bounds__(256)
void center_new_k(const float* __restrict__ sx, const float* __restrict__ center,
                  const int* __restrict__ sy, float* __restrict__ out) {
  __shared__ int syv[115];
  int tid = threadIdx.x;
  if (tid < 115) syv[tid] = sy[tid];
  __syncthreads();
  int c = blockIdx.x;
  int d = blockIdx.y * 256 + tid;
  float sum = 0.f; int cnt = 0;
  for (int s = 0; s < 115; ++s)
    if (syv[s] == c) { sum += sx[(size_t)s * 1024 + d]; ++cnt; }
  out[2 + (size_t)c * 1024 + d] =
      0.5f * (sum / (float)(cnt > 0 ? cnt : 1)) + 0.25f * center[(size_t)c * 1024 + d];
}

__global__ __launch_bounds__(256)
void finalize_k(const float* __restrict__ bpre, const int* __restrict__ sy,
                const int* __restrict__ qy, float* __restrict__ out) {
  __shared__ float bls[23][115];
  __shared__ float dis[23][23];
  __shared__ int   syv[115];
  __shared__ float ccnt[23];
  __shared__ float lossq[23];
  __shared__ float accq[23];
  const int tid = threadIdx.x;
  if (tid < 115) syv[tid] = sy[tid];
  __syncthreads();
  if (tid < 23) {
    float mx = -3.4e38f;
    for (int s = 0; s < 115; ++s) mx = fmaxf(mx, bpre[tid * 115 + s]);
    float se = 0.f;
    for (int s = 0; s < 115; ++s) se += expf(bpre[tid * 115 + s] - mx);
    float lse = mx + logf(se);
    for (int s = 0; s < 115; ++s) bls[tid][s] = bpre[tid * 115 + s] - lse;
    int c = 0;
    for (int s = 0; s < 115; ++s) c += (syv[s] == tid);
    ccnt[tid] = (float)(c > 0 ? c : 1);
  }
  __syncthreads();
  for (int i = tid; i < 23 * 23; i += 256) {
    int qq = i / 23, c = i - qq * 23;
    float sum = 0.f;
    for (int s = 0; s < 115; ++s)
      if (syv[s] == c) sum += bls[qq][s];
    dis[qq][c] = sum / ccnt[c];
  }
  __syncthreads();
  if (tid < 23) {
    int qq = tid;
    float mx = -3.4e38f; int am = 0;
    for (int c = 0; c < 23; ++c) {
      float v = dis[qq][c];
      if (v > mx) { mx = v; am = c; }
    }
    float se = 0.f;
    for (int c = 0; c < 23; ++c) se += expf(dis[qq][c] - mx);
    float lse = mx + logf(se);
    int y = qy[qq];
    lossq[qq] = -(dis[qq][y] - lse);
    accq[qq] = (am == y) ? 1.f : 0.f;
  }
  __syncthreads();
  if (tid == 0) {
    float L = 0.f, A = 0.f;
    for (int qq = 0; qq < 23; ++qq) { L += lossq[qq]; A += accq[qq]; }
    out[0] = L;
    out[1] = A;
  }
}

// ---------------------------------------------------------------------------
extern "C" void kernel_launch(void* const* d_in, const int* in_sizes, int n_in,
                              void* d_out, int out_size, void* d_ws, size_t ws_size,
                              hipStream_t stream) {
  const float* sup_x  = (const float*)d_in[0];
  const int*   sup_ei = (const int*)d_in[1];
  const int*   sup_y  = (const int*)d_in[3];
  const float* q_x    = (const float*)d_in[4];
  const int*   q_ei   = (const int*)d_in[5];
  const int*   q_y    = (const int*)d_in[7];
  const float* center = (const float*)d_in[8];
  const float* cw1    = (const float*)d_in[9];
  const float* cb1    = (const float*)d_in[10];
  const float* cwr    = (const float*)d_in[11];
  const float* cbr    = (const float*)d_in[12];
  const float* l2w    = (const float*)d_in[13];
  const float* l2b    = (const float*)d_in[14];
  const float* mw     = (const float*)d_in[15];
  const float* mb     = (const float*)d_in[16];
  float* out = (float*)d_out;

  // ---- workspace carve-up (bytes, 256-aligned) ----
  char* base = (char*)d_ws;
  size_t off = 0;
  auto alloc = [&](size_t n) { char* p = base + off; off += (n + 255) & ~(size_t)255; return p; };
  _Float16* wbuf5 = (_Float16*)alloc(5 * WL * 2);
  _Float16* w1buf = (_Float16*)alloc(2048 * 2);
  float* h1   = (float*)alloc(138 * 1024 * 4);
  float* sxb  = (float*)alloc(138 * 1024 * 4);
  float* h2p  = (float*)alloc(138 * 1024 * 4);
  float* h2   = (float*)alloc(138 * 1024 * 4);
  float* feat = (float*)alloc(138 * 1024 * 4);
  float* bpre = (float*)alloc(23 * 115 * 4);

  const size_t R1_FULL = 138ull * 64 * 64 * 64 * 2;    //  72,351,744 (L2 out, all)
  const size_t R0_FULL = 115ull * 128 * 128 * 64 * 2;  // 241,172,480 (L1 out, 115)
  const size_t R0_23   = 23ull * 128 * 128 * 64 * 2;   //  48,234,496
  const size_t R1_SML  = 12ull * 64 * 64 * 64 * 2;
  const size_t R0_SML  = 12ull * 128 * 128 * 64 * 2;

  const int tier = (ws_size >= off + R1_FULL + R0_FULL + 4096) ? 0
                 : (ws_size >= off + R1_FULL + R0_23 + 4096)   ? 1 : 2;

  _Float16* region1 = (_Float16*)alloc(tier <= 1 ? R1_FULL : R1_SML);
  _Float16* region0 = (_Float16*)alloc(tier == 0 ? R0_FULL : (tier == 1 ? R0_23 : R0_SML));
  _Float16* l3out = region0;
  _Float16* l4out = region0 + (tier <= 1 ? 9043968u : 786432u);
  _Float16* l5out = region0 + (tier <= 1 ? 11304960u : 983040u);
  _Float16* wlin2 = region0;               // overlays, dead after conv chain
  _Float16* wmlp  = region0 + 1048576u;

  wtransform<<<728, 256, 0, stream>>>(cwr, cw1, wbuf5, w1buf);

  if (tier == 0) {
    // L1+L2 full support batch, then query; L3-L6 full batch.
    conv_l1<<<dim3(16, 16, 115), 256, 0, stream>>>(sup_x, region0, w1buf, cb1);
    conv_mfma2<false><<<dim3(8, 8, 115), 128, 0, stream>>>(
        region0, region1, wbuf5, cbr, 128, 128);
    conv_l1<<<dim3(16, 16, 23), 256, 0, stream>>>(q_x, region0, w1buf, cb1);
    conv_mfma2<false><<<dim3(8, 8, 23), 128, 0, stream>>>(
        region0, region1 + 115ull * 64 * 64 * 64, wbuf5, cbr, 128, 128);
    conv_mfma2<false><<<dim3(4, 4, 138), 128, 0, stream>>>(
        region1, l3out, wbuf5 + 1 * WL, cbr + 64, 64, 64);
    conv_mfma2<false><<<dim3(2, 2, 138), 128, 0, stream>>>(
        l3out, l4out, wbuf5 + 2 * WL, cbr + 128, 32, 32);
    conv_mfma2<false><<<dim3(1, 1, 138), 128, 0, stream>>>(
        l4out, l5out, wbuf5 + 3 * WL, cbr + 192, 16, 16);
    conv_mfma<8, 8, true><<<dim3(1, 1, 138), 256, 0, stream>>>(
        l5out, h1, wbuf5 + 4 * WL, cbr + 256, 8, 8);
  } else if (tier == 1) {
    for (int c = 0; c < 6; ++c) {
      const float* xin = (c < 5) ? (sup_x + (size_t)c * 23 * 3 * 65536) : q_x;
      conv_l1<<<dim3(16, 16, 23), 256, 0, stream>>>(xin, region0, w1buf, cb1);
      conv_mfma2<false><<<dim3(8, 8, 23), 128, 0, stream>>>(
          region0, region1 + (size_t)c * 23 * 64 * 64 * 64, wbuf5, cbr, 128, 128);
    }
    conv_mfma2<false><<<dim3(4, 4, 138), 128, 0, stream>>>(
        region1, l3out, wbuf5 + 1 * WL, cbr + 64, 64, 64);
    conv_mfma2<false><<<dim3(2, 2, 138), 128, 0, stream>>>(
        l3out, l4out, wbuf5 + 2 * WL, cbr + 128, 32, 32);
    conv_mfma2<false><<<dim3(1, 1, 138), 128, 0, stream>>>(
        l4out, l5out, wbuf5 + 3 * WL, cbr + 192, 16, 16);
    conv_mfma<8, 8, true><<<dim3(1, 1, 138), 256, 0, stream>>>(
        l5out, h1, wbuf5 + 4 * WL, cbr + 256, 8, 8);
  } else {
    auto run_chain = [&](const float* xin, int n, int gb) {
      conv_l1<<<dim3(16, 16, n), 256, 0, stream>>>(xin, region0, w1buf, cb1);
      conv_mfma2<false><<<dim3(8, 8, n), 128, 0, stream>>>(
          region0, region1, wbuf5, cbr, 128, 128);
      conv_mfma2<false><<<dim3(4, 4, n), 128, 0, stream>>>(
          region1, l3out, wbuf5 + 1 * WL, cbr + 64, 64, 64);
      conv_mfma2<false><<<dim3(2, 2, n), 128, 0, stream>>>(
          l3out, l4out, wbuf5 + 2 * WL, cbr + 128, 32, 32);
      conv_mfma2<false><<<dim3(1, 1, n), 128, 0, stream>>>(
          l4out, l5out, wbuf5 + 3 * WL, cbr + 192, 16, 16);
      conv_mfma<8, 8, true><<<dim3(1, 1, n), 256, 0, stream>>>(
          l5out, h1 + (size_t)gb * 1024, wbuf5 + 4 * WL, cbr + 256, 8, 8);
    };
    for (int i0 = 0; i0 < 115; i0 += 12)
      run_chain(sup_x + (size_t)i0 * 3 * 65536, (115 - i0 < 12) ? 115 - i0 : 12, i0);
    for (int i0 = 0; i0 < 23; i0 += 12)
      run_chain(q_x + (size_t)i0 * 3 * 65536, (23 - i0 < 12) ? 23 - i0 : 12, 115 + i0);
  }

  // ---- lin weight fragments (region0 now dead) ----
  wtransform_lin<<<4096, 256, 0, stream>>>(l2w, wlin2, 32);
  wtransform_lin<<<8192, 256, 0, stream>>>(mw, wmlp, 64);

  // ---- graph layers (support rows 0..114, query rows 115..137) ----
  edge_agg_mul<<<115, 256, 0, stream>>>(h1, sup_ei, 4096, sxb);
  edge_agg_mul<<<23, 256, 0, stream>>>(h1 + 115 * 1024, q_ei, 1024, sxb + 115 * 1024);
  gemm_mfma<1024><<<dim3(32, 9), 256, 0, stream>>>(sxb, nullptr, wlin2, l2b, h2p, 138);
  edge_agg_mul<<<115, 256, 0, stream>>>(h2p, sup_ei, 4096, h2);
  edge_agg_mul<<<23, 256, 0, stream>>>(h2p + 115 * 1024, q_ei, 1024, h2 + 115 * 1024);
  gemm_mfma<2048><<<dim3(32, 9), 256, 0, stream>>>(h1, h2, wmlp, mb, feat, 138);

  // ---- metric head ----
  rbf_pairs<<<(23 * 115 * 64 + 255) / 256, 256, 0, stream>>>(
      feat, feat + 115 * 1024, center, bpre);
  center_new_k<<<dim3(23, 4), 256, 0, stream>>>(feat, center, sup_y, out);
  finalize_k<<<1, 256, 0, stream>>>(bpre, sup_y, q_y, out);
}

// Round 9
// 694.845 us; speedup vs baseline: 1.1750x; 1.1750x over previous
//
#include <hip/hip_runtime.h>
#include <cstdint>
#include <cstddef>

// ===========================================================================
// FP16 MFMA pipeline (R16 = R15 resubmitted — R8 bench was an infra failure,
// "MI355X container failed twice"; no kernel verdict obtained).
// R15 = R10 (best-known conv form: 16x16 tile, stride-72 conflict-free
// patch, single barrier, one-tap-ahead weight prefetch, lb(256,3))
//  + ASYNC-STAGE SPLIT (T14): the staging loop previously interleaved
//    load->ds_write per iteration, serializing ~10 x ~500cy of global
//    latency per block (~= the block's whole MFMA time). R9-R14 showed dur
//    pinned at ~181-183 regardless of occupancy/weight-reuse/phase-count —
//    consistent with this shared serial cost. Now: issue ALL halo loads
//    into a register array (one latency exposure, 11 in flight), then
//    drain once and ds_write. Same applied to conv_l1.
// ===========================================================================

typedef _Float16 f16x8 __attribute__((ext_vector_type(8)));
typedef __attribute__((ext_vector_type(4))) float f32x4;

#define WL 36864  // fp16 elems per transformed conv layer: 9 taps * 8 * 512

// ---------------------------------------------------------------------------
// Conv weight transform: cw_rest [5][64][64][3][3] ->
//   wbuf5 [5][tap9][cc2][nt4][64][8] fp16 ; cw1 -> w1buf [nt4][64][8] (K=27 pad 32)
// ---------------------------------------------------------------------------
__global__ __launch_bounds__(256)
void wtransform(const float* __restrict__ cwr, const float* __restrict__ cw1,
                _Float16* __restrict__ wbuf5, _Float16* __restrict__ w1buf) {
  int i = blockIdx.x * 256 + threadIdx.x;
  if (i < 184320) {
    int layer = i / 36864; int rem = i - layer * 36864;
    int tap = rem / 4096;  int r2 = rem - tap * 4096;
    int cc = r2 / 2048;    int r3 = r2 - cc * 2048;
    int nt = r3 / 512;     int r4 = r3 - nt * 512;
    int lane = r4 / 8;     int j = r4 - lane * 8;
    int ic = cc * 32 + (lane >> 4) * 8 + j;
    int oc = nt * 16 + (lane & 15);
    float w = cwr[(((size_t)layer * 64 + oc) * 64 + ic) * 9 + tap];
    wbuf5[(size_t)layer * 36864 + tap * 4096 + (cc * 4 + nt) * 512 + lane * 8 + j] =
        (_Float16)w;
  } else if (i < 184320 + 2048) {
    int e = i - 184320;
    int nt = e / 512; int r4 = e - nt * 512;
    int lane = r4 / 8; int j = r4 - lane * 8;
    int k = (lane >> 4) * 8 + j;
    float w = 0.f;
    if (k < 27) {
      int tap = k / 3, ic = k - tap * 3;
      int oc = nt * 16 + (lane & 15);
      w = cw1[((size_t)oc * 3 + ic) * 9 + tap];
    }
    w1buf[nt * 512 + lane * 8 + j] = (_Float16)w;
  }
}

// ---------------------------------------------------------------------------
// Lin weight transform: W [K,1024] -> frag [K/32][nt64][64][8] fp16.
// ---------------------------------------------------------------------------
__global__ __launch_bounds__(256)
void wtransform_lin(const float* __restrict__ w, _Float16* __restrict__ frag,
                    int KS) {
  int i = blockIdx.x * 256 + threadIdx.x;
  int total = KS * 64 * 512;
  if (i >= total) return;
  int ks = i / (64 * 512); int rem = i - ks * (64 * 512);
  int nt = rem / 512;      int r = rem - nt * 512;
  int lane = r / 8;        int j = r - lane * 8;
  int k = ks * 32 + (lane >> 4) * 8 + j;
  int n = nt * 16 + (lane & 15);
  frag[((size_t)ks * 64 + nt) * 512 + lane * 8 + j] = (_Float16)w[(size_t)k * 1024 + n];
}

// ---------------------------------------------------------------------------
// FP16 MFMA gemm: out[m,n] = sum_k A[m,k] W[k,n] + bias[n]; A fp32 rows.
// 32-col blocks, grid (32, ceil(M/16)) = 288 blocks.
// ---------------------------------------------------------------------------
template<int KTOT>
__global__ __launch_bounds__(256)
void gemm_mfma(const float* __restrict__ A1, const float* __restrict__ A2,
               const _Float16* __restrict__ frag,
               const float* __restrict__ bias, float* __restrict__ out, int M) {
  __shared__ f32x4 s_red[4][2][64];  // 8KB
  const int tid = threadIdx.x;
  const int wave = tid >> 6, lane = tid & 63;
  const int q = lane >> 4, ml = lane & 15;
  const int m0 = blockIdx.y * 16;
  const int nb = blockIdx.x;           // 32-col block
  int row = m0 + ml; if (row >= M) row = M - 1;

  f32x4 acc[2];
#pragma unroll
  for (int nt = 0; nt < 2; ++nt) acc[nt] = (f32x4){0.f, 0.f, 0.f, 0.f};

  constexpr int KSW = KTOT / 128;
  const int ksBase = wave * KSW;
#pragma unroll 2
  for (int s = 0; s < KSW; ++s) {
    int ks = ksBase + s;
    int k0 = ks * 32 + q * 8;
    const float* ap;
    if constexpr (KTOT == 2048) {
      ap = (k0 >= 1024) ? (A2 + (size_t)row * 1024 + (k0 - 1024))
                        : (A1 + (size_t)row * 1024 + k0);
    } else {
      ap = A1 + (size_t)row * 1024 + k0;
    }
    float4 va = *(const float4*)ap;
    float4 vb = *(const float4*)(ap + 4);
    f16x8 av;
    av[0] = (_Float16)va.x; av[1] = (_Float16)va.y;
    av[2] = (_Float16)va.z; av[3] = (_Float16)va.w;
    av[4] = (_Float16)vb.x; av[5] = (_Float16)vb.y;
    av[6] = (_Float16)vb.z; av[7] = (_Float16)vb.w;
    const _Float16* fb = frag + ((size_t)ks * 64 + nb * 2) * 512 + lane * 8;
#pragma unroll
    for (int nt = 0; nt < 2; ++nt) {
      f16x8 bv = *(const f16x8*)(fb + nt * 512);
      acc[nt] = __builtin_amdgcn_mfma_f32_16x16x32_f16(av, bv, acc[nt], 0, 0, 0);
    }
  }
#pragma unroll
  for (int nt = 0; nt < 2; ++nt) s_red[wave][nt][lane] = acc[nt];
  __syncthreads();
  if (wave < 2) {
    int nt = wave;
    f32x4 sum = s_red[0][nt][lane];
#pragma unroll
    for (int w2 = 1; w2 < 4; ++w2) {
      f32x4 p = s_red[w2][nt][lane];
      sum[0] += p[0]; sum[1] += p[1]; sum[2] += p[2]; sum[3] += p[3];
    }
    int n = nb * 32 + nt * 16 + ml;
    float bv = bias[n];
#pragma unroll
    for (int r = 0; r < 4; ++r) {
      int m = m0 + q * 4 + r;
      if (m < M) out[(size_t)m * 1024 + n] = sum[r] + bv;
    }
  }
}

// ---------------------------------------------------------------------------
// conv3x3(SAME)+bias+relu+maxpool2, IC=OC=64, fp16 MFMA implicit GEMM.
// 16x16 tile, 47KB stride-72 patch (conflict-free), 3 blocks/CU.
// Two-phase staging — issue all halo loads into registers (11 in flight),
// single vmcnt drain, then ds_write. One barrier. One-tap-ahead weight
// prefetch. Pooling in-register.
// ---------------------------------------------------------------------------
template<int TCX, int TCY, bool FP32OUT>
__global__ __launch_bounds__(256, 3)
void conv_mfma(const _Float16* __restrict__ act_in,
               void* __restrict__ act_out,
               const _Float16* __restrict__ wbuf,   // [9][cc2][nt4][64][8]
               const float* __restrict__ bias,
               int IH, int IW) {
  constexpr int PX = TCX + 2, PY = TCY + 2;
  constexpr int MT = (TCX * TCY) / 64;
  constexpr int TOT = PY * PX * 8;
  constexpr int ITERS = (TOT + 255) / 256;
  __shared__ __align__(16) _Float16 s_patch[PY * PX * 72];

  const int tid = threadIdx.x;
  const int wave = tid >> 6, lane = tid & 63;
  const int q = lane >> 4, ml = lane & 15;
  const int x0 = blockIdx.x * TCX, y0 = blockIdx.y * TCY;
  const int img = blockIdx.z;

  // ---- stage phase A: issue ALL loads into registers (latency overlapped)
  uint4 rbuf[ITERS];
#pragma unroll
  for (int i = 0; i < ITERS; ++i) {
    int u = tid + i * 256;
    uint4 v = {0u, 0u, 0u, 0u};
    if (u < TOT) {
      int pos = u >> 3, sub = u & 7;
      int py = pos / PX, px = pos - py * PX;
      int gy = y0 - 1 + py, gx = x0 - 1 + px;
      if ((unsigned)gy < (unsigned)IH && (unsigned)gx < (unsigned)IW)
        v = *(const uint4*)(act_in + (((size_t)img * IH + gy) * IW + gx) * 64 + sub * 8);
    }
    rbuf[i] = v;
  }
  // ---- stage phase B: write to LDS (single drain)
#pragma unroll
  for (int i = 0; i < ITERS; ++i) {
    int u = tid + i * 256;
    if (u < TOT) {
      int pos = u >> 3, sub = u & 7;
      *(uint4*)(s_patch + pos * 72 + sub * 8) = rbuf[i];
    }
  }

  // prefetch tap 0 weights (both cc chunks, 8 fragments)
  const _Float16* wl = wbuf + lane * 8;
  f16x8 bw[8], bn[8];
#pragma unroll
  for (int f = 0; f < 8; ++f) bw[f] = *(const f16x8*)(wl + f * 512);

  __syncthreads();

  f32x4 acc[MT][4];
#pragma unroll
  for (int mt = 0; mt < MT; ++mt)
#pragma unroll
    for (int nt = 0; nt < 4; ++nt)
      acc[mt][nt] = (f32x4){0.f, 0.f, 0.f, 0.f};

  int pxv[MT], pyv[MT];
#pragma unroll
  for (int mt = 0; mt < MT; ++mt) {
    int p = (wave * MT + mt) * 16 + ml;
    pxv[mt] = p % TCX;
    pyv[mt] = p / TCX;
  }

#pragma unroll 1
  for (int tap = 0; tap < 9; ++tap) {
    if (tap < 8) {
      const _Float16* np = wl + (tap + 1) * 4096;
#pragma unroll
      for (int f = 0; f < 8; ++f) bn[f] = *(const f16x8*)(np + f * 512);
    }
    const int dy = tap / 3, dx = tap - dy * 3;
#pragma unroll
    for (int cc = 0; cc < 2; ++cc) {
#pragma unroll
      for (int mt = 0; mt < MT; ++mt) {
        const _Float16* ap =
            s_patch + ((pyv[mt] + dy) * PX + (pxv[mt] + dx)) * 72 + cc * 32 + q * 8;
        f16x8 av = *(const f16x8*)ap;
#pragma unroll
        for (int nt = 0; nt < 4; ++nt)
          acc[mt][nt] = __builtin_amdgcn_mfma_f32_16x16x32_f16(av, bw[cc * 4 + nt],
                                                               acc[mt][nt], 0, 0, 0);
      }
    }
#pragma unroll
    for (int f = 0; f < 8; ++f) bw[f] = bn[f];
  }

  // ---- in-register bias+relu+2x2 maxpool + direct store ----
  const int OH = IH >> 1, OW = IW >> 1;
#pragma unroll
  for (int nt = 0; nt < 4; ++nt) {
    int oc = nt * 16 + ml;
    float bvs = bias[oc];
    if constexpr (TCX == 16) {
#pragma unroll
      for (int mh = 0; mh < MT / 2; ++mh)
#pragma unroll
        for (int rh = 0; rh < 2; ++rh) {
          float a0 = fmaxf(acc[2 * mh][nt][2 * rh] + bvs, 0.f);
          float a1 = fmaxf(acc[2 * mh][nt][2 * rh + 1] + bvs, 0.f);
          float a2 = fmaxf(acc[2 * mh + 1][nt][2 * rh] + bvs, 0.f);
          float a3 = fmaxf(acc[2 * mh + 1][nt][2 * rh + 1] + bvs, 0.f);
          float m = fmaxf(fmaxf(a0, a1), fmaxf(a2, a3));
          int gy = (y0 >> 1) + wave * (MT / 2) + mh;
          int gx = (x0 >> 1) + q * 2 + rh;
          if (FP32OUT)
            ((float*)act_out)[(((size_t)img * 64 + oc) * OH + gy) * OW + gx] = m;
          else
            ((_Float16*)act_out)[(((size_t)img * OH + gy) * OW + gx) * 64 + oc] =
                (_Float16)m;
        }
    } else {  // TCX==8, MT==1: y-pool across q>>1 via shfl_xor(32)
      float m01 = fmaxf(fmaxf(acc[0][nt][0] + bvs, 0.f), fmaxf(acc[0][nt][1] + bvs, 0.f));
      float m23 = fmaxf(fmaxf(acc[0][nt][2] + bvs, 0.f), fmaxf(acc[0][nt][3] + bvs, 0.f));
      float p0 = fmaxf(m01, __shfl_xor(m01, 32));
      float p1 = fmaxf(m23, __shfl_xor(m23, 32));
      if ((lane & 32) == 0) {
        int gy = (y0 >> 1) + wave;
        int gx0 = (x0 >> 1) + (q & 1) * 2;
        if (FP32OUT) {
          float* o = (float*)act_out + (((size_t)img * 64 + oc) * OH + gy) * OW + gx0;
          o[0] = p0; o[1] = p1;
        } else {
          _Float16* o = (_Float16*)act_out;
          o[(((size_t)img * OH + gy) * OW + gx0) * 64 + oc] = (_Float16)p0;
          o[(((size_t)img * OH + gy) * OW + gx0 + 1) * 64 + oc] = (_Float16)p1;
        }
      }
    }
  }
}

// ---------------------------------------------------------------------------
// Layer 1: IC=3, K=27 (pad 32), planar fp32 input. Tile 16x16 -> pooled 8x8.
// No im2col LDS buffer; halo staged as fp16 [3][18][18] with two-phase
// (reg-buffered) staging. Per-lane loop-invariant im2col offsets.
// ---------------------------------------------------------------------------
__global__ __launch_bounds__(256, 4)
void conv_l1(const float* __restrict__ in, _Float16* __restrict__ act_out,
             const _Float16* __restrict__ w1buf, const float* __restrict__ bias) {
  __shared__ __align__(16) _Float16 s_rawh[1280];  // [3][18][18]=972 + zero pad

  const int tid = threadIdx.x;
  const int wave = tid >> 6, lane = tid & 63;
  const int q = lane >> 4, ml = lane & 15;
  const int x0 = blockIdx.x * 16, y0 = blockIdx.y * 16;
  const int img = blockIdx.z;

  // zero pad region [972, 1280) absorbs k>=27 fragment reads
  if (tid < 308) s_rawh[972 + tid] = (_Float16)0.f;

  // two-phase staging: 4 predicated loads into regs, then convert+write
  float rv[4];
#pragma unroll
  for (int i = 0; i < 4; ++i) {
    int u = tid + i * 256;
    float v = 0.f;
    if (u < 972) {
      int ic = u / 324, rem = u - ic * 324;
      int yy = rem / 18, xx = rem - yy * 18;
      int gy = y0 - 1 + yy, gx = x0 - 1 + xx;
      if ((unsigned)gy < 256u && (unsigned)gx < 256u)
        v = in[((size_t)img * 3 + ic) * 65536 + gy * 256 + gx];
    }
    rv[i] = v;
  }
#pragma unroll
  for (int i = 0; i < 4; ++i) {
    int u = tid + i * 256;
    if (u < 972) s_rawh[u] = (_Float16)rv[i];
  }

  // per-lane loop-invariant im2col offsets (halfword units)
  int offs[8];
#pragma unroll
  for (int j = 0; j < 8; ++j) {
    int k = q * 8 + j;
    int tap = k / 3, ic = k - tap * 3;
    int ddy = tap / 3, ddx = tap - ddy * 3;
    offs[j] = (k < 27) ? (ic * 324 + ddy * 18 + ddx + ml) : 972;
  }

  f16x8 bv[4];
#pragma unroll
  for (int nt = 0; nt < 4; ++nt)
    bv[nt] = *(const f16x8*)(w1buf + nt * 512 + lane * 8);

  __syncthreads();

  f32x4 acc[4][4];
#pragma unroll
  for (int t4 = 0; t4 < 4; ++t4)
#pragma unroll
    for (int nt = 0; nt < 4; ++nt)
      acc[t4][nt] = (f32x4){0.f, 0.f, 0.f, 0.f};

#pragma unroll
  for (int t4 = 0; t4 < 4; ++t4) {
    const int tb = (wave * 4 + t4) * 18;   // t = y row within 16x16 tile
    f16x8 av;
#pragma unroll
    for (int j = 0; j < 8; ++j) av[j] = s_rawh[offs[j] + tb];
#pragma unroll
    for (int nt = 0; nt < 4; ++nt)
      acc[t4][nt] = __builtin_amdgcn_mfma_f32_16x16x32_f16(av, bv[nt], acc[t4][nt], 0, 0, 0);
  }

#pragma unroll
  for (int nt = 0; nt < 4; ++nt) {
    int oc = nt * 16 + ml;
    float bvs = bias[oc];
#pragma unroll
    for (int mh = 0; mh < 2; ++mh)
#pragma unroll
      for (int rh = 0; rh < 2; ++rh) {
        float a0 = fmaxf(acc[2 * mh][nt][2 * rh] + bvs, 0.f);
        float a1 = fmaxf(acc[2 * mh][nt][2 * rh + 1] + bvs, 0.f);
        float a2 = fmaxf(acc[2 * mh + 1][nt][2 * rh] + bvs, 0.f);
        float a3 = fmaxf(acc[2 * mh + 1][nt][2 * rh + 1] + bvs, 0.f);
        float m = fmaxf(fmaxf(a0, a1), fmaxf(a2, a3));
        int gy = blockIdx.y * 8 + wave * 2 + mh;
        int gx = blockIdx.x * 8 + q * 2 + rh;
        act_out[(((size_t)img * 128 + gy) * 128 + gx) * 64 + oc] = (_Float16)m;
      }
  }
}

// ---------------------------------------------------------------------------
// Graph aggregation (two-phase) + metric head (unchanged).
// ---------------------------------------------------------------------------
__global__ __launch_bounds__(256)
void edge_agg_mul(const float* __restrict__ h, const int* __restrict__ ei,
                  int E, float* __restrict__ out) {
  __shared__ int list[1024];
  __shared__ int cnt;
  const int n = blockIdx.x;
  const int tid = threadIdx.x;
  if (tid == 0) cnt = 0;
  __syncthreads();
  for (int e = tid; e < E; e += 256) {
    if (ei[E + e] == n) {
      int p = atomicAdd(&cnt, 1);
      list[p] = ei[e];
    }
  }
  __syncthreads();
  const int c = cnt;
  float ax = 0.f, ay = 0.f, az = 0.f, aw = 0.f;
#pragma unroll 4
  for (int i = 0; i < c; ++i) {
    const float4 v = ((const float4*)(h + (size_t)list[i] * 1024))[tid];
    ax += v.x; ay += v.y; az += v.z; aw += v.w;
  }
  float inv = 1.f / (float)(c > 0 ? c : 1);
  const float4 hv = ((const float4*)(h + (size_t)n * 1024))[tid];
  float4 o;
  o.x = ax * inv * hv.x; o.y = ay * inv * hv.y;
  o.z = az * inv * hv.z; o.w = aw * inv * hv.w;
  ((float4*)(out + (size_t)n * 1024))[tid] = o;
}

__global__ __launch_bounds__(256)
void rbf_pairs(const float* __restrict__ sx, const float* __restrict__ qx,
               const float* __restrict__ center, float* __restrict__ bpre) {
  int gid = blockIdx.x * 256 + threadIdx.x;
  int wid = gid >> 6;
  int lane = gid & 63;
  if (wid >= 23 * 115) return;
  int qq = wid / 115, s = wid - qq * 115;
  const float* sr = sx + (size_t)s * 1024;
  const float* qr = qx + (size_t)qq * 1024;
  const float* cr = center + (size_t)(s / 5) * 1024;
  float S1 = 0.f, S2 = 0.f, S3 = 0.f;
  for (int d = lane; d < 1024; d += 64) {
    float sv = sr[d], qv = qr[d];
    float df = sv - qv;
    float a = expf(-df * df);
    S1 += a;
    S2 += expf(a);
    float sc = 0.25f * cr[d] + 0.5f * sv;
    float d2 = sc - qv;
    S3 += expf(-d2 * d2);
  }
#pragma unroll
  for (int o = 32; o > 0; o >>= 1) {
    S1 += __shfl_down(S1, o);
    S2 += __shfl_down(S2, o);
    S3 += __shfl_down(S3, o);
  }
  if (lane == 0) bpre[wid] = S3 + S1 - 1024.f * logf(S2);
}

__global__ __launch_bounds__(256)
void center_new_k(const float* __restrict__ sx, const float* __restrict__ center,
                  const int* __restrict__ sy, float* __restrict__ out) {
  __shared__ int syv[115];
  int tid = threadIdx.x;
  if (tid < 115) syv[tid] = sy[tid];
  __syncthreads();
  int c = blockIdx.x;
  int d = blockIdx.y * 256 + tid;
  float sum = 0.f; int cnt = 0;
  for (int s = 0; s < 115; ++s)
    if (syv[s] == c) { sum += sx[(size_t)s * 1024 + d]; ++cnt; }
  out[2 + (size_t)c * 1024 + d] =
      0.5f * (sum / (float)(cnt > 0 ? cnt : 1)) + 0.25f * center[(size_t)c * 1024 + d];
}

__global__ __launch_bounds__(256)
void finalize_k(const float* __restrict__ bpre, const int* __restrict__ sy,
                const int* __restrict__ qy, float* __restrict__ out) {
  __shared__ float bls[23][115];
  __shared__ float dis[23][23];
  __shared__ int   syv[115];
  __shared__ float ccnt[23];
  __shared__ float lossq[23];
  __shared__ float accq[23];
  const int tid = threadIdx.x;
  if (tid < 115) syv[tid] = sy[tid];
  __syncthreads();
  if (tid < 23) {
    float mx = -3.4e38f;
    for (int s = 0; s < 115; ++s) mx = fmaxf(mx, bpre[tid * 115 + s]);
    float se = 0.f;
    for (int s = 0; s < 115; ++s) se += expf(bpre[tid * 115 + s] - mx);
    float lse = mx + logf(se);
    for (int s = 0; s < 115; ++s) bls[tid][s] = bpre[tid * 115 + s] - lse;
    int c = 0;
    for (int s = 0; s < 115; ++s) c += (syv[s] == tid);
    ccnt[tid] = (float)(c > 0 ? c : 1);
  }
  __syncthreads();
  for (int i = tid; i < 23 * 23; i += 256) {
    int qq = i / 23, c = i - qq * 23;
    float sum = 0.f;
    for (int s = 0; s < 115; ++s)
      if (syv[s] == c) sum += bls[qq][s];
    dis[qq][c] = sum / ccnt[c];
  }
  __syncthreads();
  if (tid < 23) {
    int qq = tid;
    float mx = -3.4e38f; int am = 0;
    for (int c = 0; c < 23; ++c) {
      float v = dis[qq][c];
      if (v > mx) { mx = v; am = c; }
    }
    float se = 0.f;
    for (int c = 0; c < 23; ++c) se += expf(dis[qq][c] - mx);
    float lse = mx + logf(se);
    int y = qy[qq];
    lossq[qq] = -(dis[qq][y] - lse);
    accq[qq] = (am == y) ? 1.f : 0.f;
  }
  __syncthreads();
  if (tid == 0) {
    float L = 0.f, A = 0.f;
    for (int qq = 0; qq < 23; ++qq) { L += lossq[qq]; A += accq[qq]; }
    out[0] = L;
    out[1] = A;
  }
}

// ---------------------------------------------------------------------------
extern "C" void kernel_launch(void* const* d_in, const int* in_sizes, int n_in,
                              void* d_out, int out_size, void* d_ws, size_t ws_size,
                              hipStream_t stream) {
  const float* sup_x  = (const float*)d_in[0];
  const int*   sup_ei = (const int*)d_in[1];
  const int*   sup_y  = (const int*)d_in[3];
  const float* q_x    = (const float*)d_in[4];
  const int*   q_ei   = (const int*)d_in[5];
  const int*   q_y    = (const int*)d_in[7];
  const float* center = (const float*)d_in[8];
  const float* cw1    = (const float*)d_in[9];
  const float* cb1    = (const float*)d_in[10];
  const float* cwr    = (const float*)d_in[11];
  const float* cbr    = (const float*)d_in[12];
  const float* l2w    = (const float*)d_in[13];
  const float* l2b    = (const float*)d_in[14];
  const float* mw     = (const float*)d_in[15];
  const float* mb     = (const float*)d_in[16];
  float* out = (float*)d_out;

  // ---- workspace carve-up (bytes, 256-aligned) ----
  char* base = (char*)d_ws;
  size_t off = 0;
  auto alloc = [&](size_t n) { char* p = base + off; off += (n + 255) & ~(size_t)255; return p; };
  _Float16* wbuf5 = (_Float16*)alloc(5 * WL * 2);
  _Float16* w1buf = (_Float16*)alloc(2048 * 2);
  float* h1   = (float*)alloc(138 * 1024 * 4);
  float* sxb  = (float*)alloc(138 * 1024 * 4);
  float* h2p  = (float*)alloc(138 * 1024 * 4);
  float* h2   = (float*)alloc(138 * 1024 * 4);
  float* feat = (float*)alloc(138 * 1024 * 4);
  float* bpre = (float*)alloc(23 * 115 * 4);

  const size_t R1_FULL = 138ull * 64 * 64 * 64 * 2;    //  72,351,744 (L2 out, all)
  const size_t R0_FULL = 115ull * 128 * 128 * 64 * 2;  // 241,172,480 (L1 out, 115)
  const size_t R0_23   = 23ull * 128 * 128 * 64 * 2;   //  48,234,496
  const size_t R1_SML  = 12ull * 64 * 64 * 64 * 2;
  const size_t R0_SML  = 12ull * 128 * 128 * 64 * 2;

  const int tier = (ws_size >= off + R1_FULL + R0_FULL + 4096) ? 0
                 : (ws_size >= off + R1_FULL + R0_23 + 4096)   ? 1 : 2;

  _Float16* region1 = (_Float16*)alloc(tier <= 1 ? R1_FULL : R1_SML);
  _Float16* region0 = (_Float16*)alloc(tier == 0 ? R0_FULL : (tier == 1 ? R0_23 : R0_SML));
  _Float16* l3out = region0;
  _Float16* l4out = region0 + (tier <= 1 ? 9043968u : 786432u);
  _Float16* l5out = region0 + (tier <= 1 ? 11304960u : 983040u);
  _Float16* wlin2 = region0;               // overlays, dead after conv chain
  _Float16* wmlp  = region0 + 1048576u;

  wtransform<<<728, 256, 0, stream>>>(cwr, cw1, wbuf5, w1buf);

  if (tier == 0) {
    // L1+L2 full support batch, then query; L3-L6 full batch.
    conv_l1<<<dim3(16, 16, 115), 256, 0, stream>>>(sup_x, region0, w1buf, cb1);
    conv_mfma<16, 16, false><<<dim3(8, 8, 115), 256, 0, stream>>>(
        region0, region1, wbuf5, cbr, 128, 128);
    conv_l1<<<dim3(16, 16, 23), 256, 0, stream>>>(q_x, region0, w1buf, cb1);
    conv_mfma<16, 16, false><<<dim3(8, 8, 23), 256, 0, stream>>>(
        region0, region1 + 115ull * 64 * 64 * 64, wbuf5, cbr, 128, 128);
    conv_mfma<16, 16, false><<<dim3(4, 4, 138), 256, 0, stream>>>(
        region1, l3out, wbuf5 + 1 * WL, cbr + 64, 64, 64);
    conv_mfma<16, 16, false><<<dim3(2, 2, 138), 256, 0, stream>>>(
        l3out, l4out, wbuf5 + 2 * WL, cbr + 128, 32, 32);
    conv_mfma<16, 16, false><<<dim3(1, 1, 138), 256, 0, stream>>>(
        l4out, l5out, wbuf5 + 3 * WL, cbr + 192, 16, 16);
    conv_mfma<8, 8, true><<<dim3(1, 1, 138), 256, 0, stream>>>(
        l5out, h1, wbuf5 + 4 * WL, cbr + 256, 8, 8);
  } else if (tier == 1) {
    for (int c = 0; c < 6; ++c) {
      const float* xin = (c < 5) ? (sup_x + (size_t)c * 23 * 3 * 65536) : q_x;
      conv_l1<<<dim3(16, 16, 23), 256, 0, stream>>>(xin, region0, w1buf, cb1);
      conv_mfma<16, 16, false><<<dim3(8, 8, 23), 256, 0, stream>>>(
          region0, region1 + (size_t)c * 23 * 64 * 64 * 64, wbuf5, cbr, 128, 128);
    }
    conv_mfma<16, 16, false><<<dim3(4, 4, 138), 256, 0, stream>>>(
        region1, l3out, wbuf5 + 1 * WL, cbr + 64, 64, 64);
    conv_mfma<16, 16, false><<<dim3(2, 2, 138), 256, 0, stream>>>(
        l3out, l4out, wbuf5 + 2 * WL, cbr + 128, 32, 32);
    conv_mfma<16, 16, false><<<dim3(1, 1, 138), 256, 0, stream>>>(
        l4out, l5out, wbuf5 + 3 * WL, cbr + 192, 16, 16);
    conv_mfma<8, 8, true><<<dim3(1, 1, 138), 256, 0, stream>>>(
        l5out, h1, wbuf5 + 4 * WL, cbr + 256, 8, 8);
  } else {
    auto run_chain = [&](const float* xin, int n, int gb) {
      conv_l1<<<dim3(16, 16, n), 256, 0, stream>>>(xin, region0, w1buf, cb1);
      conv_mfma<16, 16, false><<<dim3(8, 8, n), 256, 0, stream>>>(
          region0, region1, wbuf5, cbr, 128, 128);
      conv_mfma<16, 16, false><<<dim3(4, 4, n), 256, 0, stream>>>(
          region1, l3out, wbuf5 + 1 * WL, cbr + 64, 64, 64);
      conv_mfma<16, 16, false><<<dim3(2, 2, n), 256, 0, stream>>>(
          l3out, l4out, wbuf5 + 2 * WL, cbr + 128, 32, 32);
      conv_mfma<16, 16, false><<<dim3(1, 1, n), 256, 0, stream>>>(
          l4out, l5out, wbuf5 + 3 * WL, cbr + 192, 16, 16);
      conv_mfma<8, 8, true><<<dim3(1, 1, n), 256, 0, stream>>>(
          l5out, h1 + (size_t)gb * 1024, wbuf5 + 4 * WL, cbr + 256, 8, 8);
    };
    for (int i0 = 0; i0 < 115; i0 += 12)
      run_chain(sup_x + (size_t)i0 * 3 * 65536, (115 - i0 < 12) ? 115 - i0 : 12, i0);
    for (int i0 = 0; i0 < 23; i0 += 12)
      run_chain(q_x + (size_t)i0 * 3 * 65536, (23 - i0 < 12) ? 23 - i0 : 12, 115 + i0);
  }

  // ---- lin weight fragments (region0 now dead) ----
  wtransform_lin<<<4096, 256, 0, stream>>>(l2w, wlin2, 32);
  wtransform_lin<<<8192, 256, 0, stream>>>(mw, wmlp, 64);

  // ---- graph layers (support rows 0..114, query rows 115..137) ----
  edge_agg_mul<<<115, 256, 0, stream>>>(h1, sup_ei, 4096, sxb);
  edge_agg_mul<<<23, 256, 0, stream>>>(h1 + 115 * 1024, q_ei, 1024, sxb + 115 * 1024);
  gemm_mfma<1024><<<dim3(32, 9), 256, 0, stream>>>(sxb, nullptr, wlin2, l2b, h2p, 138);
  edge_agg_mul<<<115, 256, 0, stream>>>(h2p, sup_ei, 4096, h2);
  edge_agg_mul<<<23, 256, 0, stream>>>(h2p + 115 * 1024, q_ei, 1024, h2 + 115 * 1024);
  gemm_mfma<2048><<<dim3(32, 9), 256, 0, stream>>>(h1, h2, wmlp, mb, feat, 138);

  // ---- metric head ----
  rbf_pairs<<<(23 * 115 * 64 + 255) / 256, 256, 0, stream>>>(
      feat, feat + 115 * 1024, center, bpre);
  center_new_k<<<dim3(23, 4), 256, 0, stream>>>(feat, center, sup_y, out);
  finalize_k<<<1, 256, 0, stream>>>(bpre, sup_y, q_y, out);
}

// Round 10
// 694.000 us; speedup vs baseline: 1.1764x; 1.0012x over previous
//
#include <hip/hip_runtime.h>
#include <cstdint>
#include <cstddef>

// ===========================================================================
// FP16 MFMA pipeline (R17).
// R17 changes vs R16 (695us; T14 async-stage split confirmed: conv_mfma
// left the top-5, conv_l1@160us now leads, VALUBusy 51 / MfmaUtil 8 /
// HBM 32% => VALU+VMEM-issue bound):
//  (1) Vectorized epilogue via LDS transpose for conv_l1 and the
//      conv_mfma<16,16,fp16> path: the old epilogue did 16 scalar u16
//      stores/thread (oc stride-16 per thread -> unpackable in-register)
//      with ~16 64-bit address chains. Now: pooled values -> LDS
//      [64 pos][stride 72] (q-groups on disjoint bank octets), barrier,
//      2 x uint4 coalesced stores/thread (wave = 1KB contiguous).
//      conv_l1: +9.2KB LDS (total 11.8KB, occupancy unchanged).
//      conv_mfma: reuses dead s_patch (one extra barrier, no LDS cost).
// ===========================================================================

typedef _Float16 f16x8 __attribute__((ext_vector_type(8)));
typedef __attribute__((ext_vector_type(4))) float f32x4;

#define WL 36864  // fp16 elems per transformed conv layer: 9 taps * 8 * 512

// ---------------------------------------------------------------------------
// Conv weight transform: cw_rest [5][64][64][3][3] ->
//   wbuf5 [5][tap9][cc2][nt4][64][8] fp16 ; cw1 -> w1buf [nt4][64][8] (K=27 pad 32)
// ---------------------------------------------------------------------------
__global__ __launch_bounds__(256)
void wtransform(const float* __restrict__ cwr, const float* __restrict__ cw1,
                _Float16* __restrict__ wbuf5, _Float16* __restrict__ w1buf) {
  int i = blockIdx.x * 256 + threadIdx.x;
  if (i < 184320) {
    int layer = i / 36864; int rem = i - layer * 36864;
    int tap = rem / 4096;  int r2 = rem - tap * 4096;
    int cc = r2 / 2048;    int r3 = r2 - cc * 2048;
    int nt = r3 / 512;     int r4 = r3 - nt * 512;
    int lane = r4 / 8;     int j = r4 - lane * 8;
    int ic = cc * 32 + (lane >> 4) * 8 + j;
    int oc = nt * 16 + (lane & 15);
    float w = cwr[(((size_t)layer * 64 + oc) * 64 + ic) * 9 + tap];
    wbuf5[(size_t)layer * 36864 + tap * 4096 + (cc * 4 + nt) * 512 + lane * 8 + j] =
        (_Float16)w;
  } else if (i < 184320 + 2048) {
    int e = i - 184320;
    int nt = e / 512; int r4 = e - nt * 512;
    int lane = r4 / 8; int j = r4 - lane * 8;
    int k = (lane >> 4) * 8 + j;
    float w = 0.f;
    if (k < 27) {
      int tap = k / 3, ic = k - tap * 3;
      int oc = nt * 16 + (lane & 15);
      w = cw1[((size_t)oc * 3 + ic) * 9 + tap];
    }
    w1buf[nt * 512 + lane * 8 + j] = (_Float16)w;
  }
}

// ---------------------------------------------------------------------------
// Lin weight transform: W [K,1024] -> frag [K/32][nt64][64][8] fp16.
// ---------------------------------------------------------------------------
__global__ __launch_bounds__(256)
void wtransform_lin(const float* __restrict__ w, _Float16* __restrict__ frag,
                    int KS) {
  int i = blockIdx.x * 256 + threadIdx.x;
  int total = KS * 64 * 512;
  if (i >= total) return;
  int ks = i / (64 * 512); int rem = i - ks * (64 * 512);
  int nt = rem / 512;      int r = rem - nt * 512;
  int lane = r / 8;        int j = r - lane * 8;
  int k = ks * 32 + (lane >> 4) * 8 + j;
  int n = nt * 16 + (lane & 15);
  frag[((size_t)ks * 64 + nt) * 512 + lane * 8 + j] = (_Float16)w[(size_t)k * 1024 + n];
}

// ---------------------------------------------------------------------------
// FP16 MFMA gemm: out[m,n] = sum_k A[m,k] W[k,n] + bias[n]; A fp32 rows.
// 32-col blocks, grid (32, ceil(M/16)) = 288 blocks.
// ---------------------------------------------------------------------------
template<int KTOT>
__global__ __launch_bounds__(256)
void gemm_mfma(const float* __restrict__ A1, const float* __restrict__ A2,
               const _Float16* __restrict__ frag,
               const float* __restrict__ bias, float* __restrict__ out, int M) {
  __shared__ f32x4 s_red[4][2][64];  // 8KB
  const int tid = threadIdx.x;
  const int wave = tid >> 6, lane = tid & 63;
  const int q = lane >> 4, ml = lane & 15;
  const int m0 = blockIdx.y * 16;
  const int nb = blockIdx.x;           // 32-col block
  int row = m0 + ml; if (row >= M) row = M - 1;

  f32x4 acc[2];
#pragma unroll
  for (int nt = 0; nt < 2; ++nt) acc[nt] = (f32x4){0.f, 0.f, 0.f, 0.f};

  constexpr int KSW = KTOT / 128;
  const int ksBase = wave * KSW;
#pragma unroll 2
  for (int s = 0; s < KSW; ++s) {
    int ks = ksBase + s;
    int k0 = ks * 32 + q * 8;
    const float* ap;
    if constexpr (KTOT == 2048) {
      ap = (k0 >= 1024) ? (A2 + (size_t)row * 1024 + (k0 - 1024))
                        : (A1 + (size_t)row * 1024 + k0);
    } else {
      ap = A1 + (size_t)row * 1024 + k0;
    }
    float4 va = *(const float4*)ap;
    float4 vb = *(const float4*)(ap + 4);
    f16x8 av;
    av[0] = (_Float16)va.x; av[1] = (_Float16)va.y;
    av[2] = (_Float16)va.z; av[3] = (_Float16)va.w;
    av[4] = (_Float16)vb.x; av[5] = (_Float16)vb.y;
    av[6] = (_Float16)vb.z; av[7] = (_Float16)vb.w;
    const _Float16* fb = frag + ((size_t)ks * 64 + nb * 2) * 512 + lane * 8;
#pragma unroll
    for (int nt = 0; nt < 2; ++nt) {
      f16x8 bv = *(const f16x8*)(fb + nt * 512);
      acc[nt] = __builtin_amdgcn_mfma_f32_16x16x32_f16(av, bv, acc[nt], 0, 0, 0);
    }
  }
#pragma unroll
  for (int nt = 0; nt < 2; ++nt) s_red[wave][nt][lane] = acc[nt];
  __syncthreads();
  if (wave < 2) {
    int nt = wave;
    f32x4 sum = s_red[0][nt][lane];
#pragma unroll
    for (int w2 = 1; w2 < 4; ++w2) {
      f32x4 p = s_red[w2][nt][lane];
      sum[0] += p[0]; sum[1] += p[1]; sum[2] += p[2]; sum[3] += p[3];
    }
    int n = nb * 32 + nt * 16 + ml;
    float bv = bias[n];
#pragma unroll
    for (int r = 0; r < 4; ++r) {
      int m = m0 + q * 4 + r;
      if (m < M) out[(size_t)m * 1024 + n] = sum[r] + bv;
    }
  }
}

// ---------------------------------------------------------------------------
// conv3x3(SAME)+bias+relu+maxpool2, IC=OC=64, fp16 MFMA implicit GEMM.
// 16x16 tile, 47KB stride-72 patch (conflict-free), 3 blocks/CU.
// Two-phase staging (T14) + one-tap-ahead weight prefetch.
// R17: fp16-out epilogue goes through an LDS transpose (reusing dead
// s_patch) -> 2 coalesced uint4 stores per thread.
// ---------------------------------------------------------------------------
template<int TCX, int TCY, bool FP32OUT>
__global__ __launch_bounds__(256, 3)
void conv_mfma(const _Float16* __restrict__ act_in,
               void* __restrict__ act_out,
               const _Float16* __restrict__ wbuf,   // [9][cc2][nt4][64][8]
               const float* __restrict__ bias,
               int IH, int IW) {
  constexpr int PX = TCX + 2, PY = TCY + 2;
  constexpr int MT = (TCX * TCY) / 64;
  constexpr int TOT = PY * PX * 8;
  constexpr int ITERS = (TOT + 255) / 256;
  __shared__ __align__(16) _Float16 s_patch[PY * PX * 72];

  const int tid = threadIdx.x;
  const int wave = tid >> 6, lane = tid & 63;
  const int q = lane >> 4, ml = lane & 15;
  const int x0 = blockIdx.x * TCX, y0 = blockIdx.y * TCY;
  const int img = blockIdx.z;

  // ---- stage phase A: issue ALL loads into registers (latency overlapped)
  uint4 rbuf[ITERS];
#pragma unroll
  for (int i = 0; i < ITERS; ++i) {
    int u = tid + i * 256;
    uint4 v = {0u, 0u, 0u, 0u};
    if (u < TOT) {
      int pos = u >> 3, sub = u & 7;
      int py = pos / PX, px = pos - py * PX;
      int gy = y0 - 1 + py, gx = x0 - 1 + px;
      if ((unsigned)gy < (unsigned)IH && (unsigned)gx < (unsigned)IW)
        v = *(const uint4*)(act_in + (((size_t)img * IH + gy) * IW + gx) * 64 + sub * 8);
    }
    rbuf[i] = v;
  }
  // ---- stage phase B: write to LDS (single drain)
#pragma unroll
  for (int i = 0; i < ITERS; ++i) {
    int u = tid + i * 256;
    if (u < TOT) {
      int pos = u >> 3, sub = u & 7;
      *(uint4*)(s_patch + pos * 72 + sub * 8) = rbuf[i];
    }
  }

  // prefetch tap 0 weights (both cc chunks, 8 fragments)
  const _Float16* wl = wbuf + lane * 8;
  f16x8 bw[8], bn[8];
#pragma unroll
  for (int f = 0; f < 8; ++f) bw[f] = *(const f16x8*)(wl + f * 512);

  __syncthreads();

  f32x4 acc[MT][4];
#pragma unroll
  for (int mt = 0; mt < MT; ++mt)
#pragma unroll
    for (int nt = 0; nt < 4; ++nt)
      acc[mt][nt] = (f32x4){0.f, 0.f, 0.f, 0.f};

  int pxv[MT], pyv[MT];
#pragma unroll
  for (int mt = 0; mt < MT; ++mt) {
    int p = (wave * MT + mt) * 16 + ml;
    pxv[mt] = p % TCX;
    pyv[mt] = p / TCX;
  }

#pragma unroll 1
  for (int tap = 0; tap < 9; ++tap) {
    if (tap < 8) {
      const _Float16* np = wl + (tap + 1) * 4096;
#pragma unroll
      for (int f = 0; f < 8; ++f) bn[f] = *(const f16x8*)(np + f * 512);
    }
    const int dy = tap / 3, dx = tap - dy * 3;
#pragma unroll
    for (int cc = 0; cc < 2; ++cc) {
#pragma unroll
      for (int mt = 0; mt < MT; ++mt) {
        const _Float16* ap =
            s_patch + ((pyv[mt] + dy) * PX + (pxv[mt] + dx)) * 72 + cc * 32 + q * 8;
        f16x8 av = *(const f16x8*)ap;
#pragma unroll
        for (int nt = 0; nt < 4; ++nt)
          acc[mt][nt] = __builtin_amdgcn_mfma_f32_16x16x32_f16(av, bw[cc * 4 + nt],
                                                               acc[mt][nt], 0, 0, 0);
      }
    }
#pragma unroll
    for (int f = 0; f < 8; ++f) bw[f] = bn[f];
  }

  // ---- bias+relu+2x2 maxpool + store ----
  const int OH = IH >> 1, OW = IW >> 1;
  if constexpr (TCX == 16 && !FP32OUT) {
    // LDS-transpose epilogue: pooled [8y][8x][64oc] staged at stride 72,
    // then 2 coalesced uint4 stores per thread.
    _Float16* s_out = s_patch;          // s_patch dead after tap loop
    __syncthreads();                    // all waves done reading s_patch
#pragma unroll
    for (int nt = 0; nt < 4; ++nt) {
      int oc = nt * 16 + ml;
      float bvs = bias[oc];
#pragma unroll
      for (int mh = 0; mh < MT / 2; ++mh)
#pragma unroll
        for (int rh = 0; rh < 2; ++rh) {
          float a0 = fmaxf(acc[2 * mh][nt][2 * rh] + bvs, 0.f);
          float a1 = fmaxf(acc[2 * mh][nt][2 * rh + 1] + bvs, 0.f);
          float a2 = fmaxf(acc[2 * mh + 1][nt][2 * rh] + bvs, 0.f);
          float a3 = fmaxf(acc[2 * mh + 1][nt][2 * rh + 1] + bvs, 0.f);
          float m = fmaxf(fmaxf(a0, a1), fmaxf(a2, a3));
          int lp = (wave * (MT / 2) + mh) * 8 + q * 2 + rh;   // local pooled pos
          s_out[lp * 72 + oc] = (_Float16)m;
        }
    }
    __syncthreads();
#pragma unroll
    for (int i = 0; i < 2; ++i) {
      int u = tid + i * 256;            // 512 uint4s total
      int pos = u >> 3, sub = u & 7;
      uint4 v = *(const uint4*)(s_out + pos * 72 + sub * 8);
      int gy = (y0 >> 1) + (pos >> 3);
      int gx = (x0 >> 1) + (pos & 7);
      *(uint4*)((_Float16*)act_out + (((size_t)img * OH + gy) * OW + gx) * 64 + sub * 8) = v;
    }
  } else {
#pragma unroll
    for (int nt = 0; nt < 4; ++nt) {
      int oc = nt * 16 + ml;
      float bvs = bias[oc];
      if constexpr (TCX == 16) {
#pragma unroll
        for (int mh = 0; mh < MT / 2; ++mh)
#pragma unroll
          for (int rh = 0; rh < 2; ++rh) {
            float a0 = fmaxf(acc[2 * mh][nt][2 * rh] + bvs, 0.f);
            float a1 = fmaxf(acc[2 * mh][nt][2 * rh + 1] + bvs, 0.f);
            float a2 = fmaxf(acc[2 * mh + 1][nt][2 * rh] + bvs, 0.f);
            float a3 = fmaxf(acc[2 * mh + 1][nt][2 * rh + 1] + bvs, 0.f);
            float m = fmaxf(fmaxf(a0, a1), fmaxf(a2, a3));
            int gy = (y0 >> 1) + wave * (MT / 2) + mh;
            int gx = (x0 >> 1) + q * 2 + rh;
            ((float*)act_out)[(((size_t)img * 64 + oc) * OH + gy) * OW + gx] = m;
          }
      } else {  // TCX==8, MT==1: y-pool across q>>1 via shfl_xor(32)
        float m01 = fmaxf(fmaxf(acc[0][nt][0] + bvs, 0.f), fmaxf(acc[0][nt][1] + bvs, 0.f));
        float m23 = fmaxf(fmaxf(acc[0][nt][2] + bvs, 0.f), fmaxf(acc[0][nt][3] + bvs, 0.f));
        float p0 = fmaxf(m01, __shfl_xor(m01, 32));
        float p1 = fmaxf(m23, __shfl_xor(m23, 32));
        if ((lane & 32) == 0) {
          int gy = (y0 >> 1) + wave;
          int gx0 = (x0 >> 1) + (q & 1) * 2;
          if (FP32OUT) {
            float* o = (float*)act_out + (((size_t)img * 64 + oc) * OH + gy) * OW + gx0;
            o[0] = p0; o[1] = p1;
          } else {
            _Float16* o = (_Float16*)act_out;
            o[(((size_t)img * OH + gy) * OW + gx0) * 64 + oc] = (_Float16)p0;
            o[(((size_t)img * OH + gy) * OW + gx0 + 1) * 64 + oc] = (_Float16)p1;
          }
        }
      }
    }
  }
}

// ---------------------------------------------------------------------------
// Layer 1: IC=3, K=27 (pad 32), planar fp32 input. Tile 16x16 -> pooled 8x8.
// Halo staged as fp16 [3][18][18] with two-phase staging; per-lane
// loop-invariant im2col offsets. R17: LDS-transpose epilogue ->
// 2 coalesced uint4 stores per thread.
// ---------------------------------------------------------------------------
__global__ __launch_bounds__(256, 4)
void conv_l1(const float* __restrict__ in, _Float16* __restrict__ act_out,
             const _Float16* __restrict__ w1buf, const float* __restrict__ bias) {
  __shared__ __align__(16) _Float16 s_rawh[1280];  // [3][18][18]=972 + zero pad
  __shared__ __align__(16) _Float16 s_out[64 * 72]; // pooled [64 pos][72] 9.2KB

  const int tid = threadIdx.x;
  const int wave = tid >> 6, lane = tid & 63;
  const int q = lane >> 4, ml = lane & 15;
  const int x0 = blockIdx.x * 16, y0 = blockIdx.y * 16;
  const int img = blockIdx.z;

  // zero pad region [972, 1280) absorbs k>=27 fragment reads
  if (tid < 308) s_rawh[972 + tid] = (_Float16)0.f;

  // two-phase staging: 4 predicated loads into regs, then convert+write
  float rv[4];
#pragma unroll
  for (int i = 0; i < 4; ++i) {
    int u = tid + i * 256;
    float v = 0.f;
    if (u < 972) {
      int ic = u / 324, rem = u - ic * 324;
      int yy = rem / 18, xx = rem - yy * 18;
      int gy = y0 - 1 + yy, gx = x0 - 1 + xx;
      if ((unsigned)gy < 256u && (unsigned)gx < 256u)
        v = in[((size_t)img * 3 + ic) * 65536 + gy * 256 + gx];
    }
    rv[i] = v;
  }
#pragma unroll
  for (int i = 0; i < 4; ++i) {
    int u = tid + i * 256;
    if (u < 972) s_rawh[u] = (_Float16)rv[i];
  }

  // per-lane loop-invariant im2col offsets (halfword units)
  int offs[8];
#pragma unroll
  for (int j = 0; j < 8; ++j) {
    int k = q * 8 + j;
    int tap = k / 3, ic = k - tap * 3;
    int ddy = tap / 3, ddx = tap - ddy * 3;
    offs[j] = (k < 27) ? (ic * 324 + ddy * 18 + ddx + ml) : 972;
  }

  f16x8 bv[4];
#pragma unroll
  for (int nt = 0; nt < 4; ++nt)
    bv[nt] = *(const f16x8*)(w1buf + nt * 512 + lane * 8);

  __syncthreads();

  f32x4 acc[4][4];
#pragma unroll
  for (int t4 = 0; t4 < 4; ++t4)
#pragma unroll
    for (int nt = 0; nt < 4; ++nt)
      acc[t4][nt] = (f32x4){0.f, 0.f, 0.f, 0.f};

#pragma unroll
  for (int t4 = 0; t4 < 4; ++t4) {
    const int tb = (wave * 4 + t4) * 18;   // t = y row within 16x16 tile
    f16x8 av;
#pragma unroll
    for (int j = 0; j < 8; ++j) av[j] = s_rawh[offs[j] + tb];
#pragma unroll
    for (int nt = 0; nt < 4; ++nt)
      acc[t4][nt] = __builtin_amdgcn_mfma_f32_16x16x32_f16(av, bv[nt], acc[t4][nt], 0, 0, 0);
  }

  // ---- LDS-transpose epilogue ----
#pragma unroll
  for (int nt = 0; nt < 4; ++nt) {
    int oc = nt * 16 + ml;
    float bvs = bias[oc];
#pragma unroll
    for (int mh = 0; mh < 2; ++mh)
#pragma unroll
      for (int rh = 0; rh < 2; ++rh) {
        float a0 = fmaxf(acc[2 * mh][nt][2 * rh] + bvs, 0.f);
        float a1 = fmaxf(acc[2 * mh][nt][2 * rh + 1] + bvs, 0.f);
        float a2 = fmaxf(acc[2 * mh + 1][nt][2 * rh] + bvs, 0.f);
        float a3 = fmaxf(acc[2 * mh + 1][nt][2 * rh + 1] + bvs, 0.f);
        float m = fmaxf(fmaxf(a0, a1), fmaxf(a2, a3));
        int lp = (wave * 2 + mh) * 8 + q * 2 + rh;
        s_out[lp * 72 + oc] = (_Float16)m;
      }
  }
  __syncthreads();
#pragma unroll
  for (int i = 0; i < 2; ++i) {
    int u = tid + i * 256;
    int pos = u >> 3, sub = u & 7;
    uint4 v = *(const uint4*)(s_out + pos * 72 + sub * 8);
    int gy = blockIdx.y * 8 + (pos >> 3);
    int gx = blockIdx.x * 8 + (pos & 7);
    *(uint4*)(act_out + (((size_t)img * 128 + gy) * 128 + gx) * 64 + sub * 8) = v;
  }
}

// ---------------------------------------------------------------------------
// Graph aggregation (two-phase) + metric head (unchanged).
// ---------------------------------------------------------------------------
__global__ __launch_bounds__(256)
void edge_agg_mul(const float* __restrict__ h, const int* __restrict__ ei,
                  int E, float* __restrict__ out) {
  __shared__ int list[1024];
  __shared__ int cnt;
  const int n = blockIdx.x;
  const int tid = threadIdx.x;
  if (tid == 0) cnt = 0;
  __syncthreads();
  for (int e = tid; e < E; e += 256) {
    if (ei[E + e] == n) {
      int p = atomicAdd(&cnt, 1);
      list[p] = ei[e];
    }
  }
  __syncthreads();
  const int c = cnt;
  float ax = 0.f, ay = 0.f, az = 0.f, aw = 0.f;
#pragma unroll 4
  for (int i = 0; i < c; ++i) {
    const float4 v = ((const float4*)(h + (size_t)list[i] * 1024))[tid];
    ax += v.x; ay += v.y; az += v.z; aw += v.w;
  }
  float inv = 1.f / (float)(c > 0 ? c : 1);
  const float4 hv = ((const float4*)(h + (size_t)n * 1024))[tid];
  float4 o;
  o.x = ax * inv * hv.x; o.y = ay * inv * hv.y;
  o.z = az * inv * hv.z; o.w = aw * inv * hv.w;
  ((float4*)(out + (size_t)n * 1024))[tid] = o;
}

__global__ __launch_bounds__(256)
void rbf_pairs(const float* __restrict__ sx, const float* __restrict__ qx,
               const float* __restrict__ center, float* __restrict__ bpre) {
  int gid = blockIdx.x * 256 + threadIdx.x;
  int wid = gid >> 6;
  int lane = gid & 63;
  if (wid >= 23 * 115) return;
  int qq = wid / 115, s = wid - qq * 115;
  const float* sr = sx + (size_t)s * 1024;
  const float* qr = qx + (size_t)qq * 1024;
  const float* cr = center + (size_t)(s / 5) * 1024;
  float S1 = 0.f, S2 = 0.f, S3 = 0.f;
  for (int d = lane; d < 1024; d += 64) {
    float sv = sr[d], qv = qr[d];
    float df = sv - qv;
    float a = expf(-df * df);
    S1 += a;
    S2 += expf(a);
    float sc = 0.25f * cr[d] + 0.5f * sv;
    float d2 = sc - qv;
    S3 += expf(-d2 * d2);
  }
#pragma unroll
  for (int o = 32; o > 0; o >>= 1) {
    S1 += __shfl_down(S1, o);
    S2 += __shfl_down(S2, o);
    S3 += __shfl_down(S3, o);
  }
  if (lane == 0) bpre[wid] = S3 + S1 - 1024.f * logf(S2);
}

__global__ __launch_bounds__(256)
void center_new_k(const float* __restrict__ sx, const float* __restrict__ center,
                  const int* __restrict__ sy, float* __restrict__ out) {
  __shared__ int syv[115];
  int tid = threadIdx.x;
  if (tid < 115) syv[tid] = sy[tid];
  __syncthreads();
  int c = blockIdx.x;
  int d = blockIdx.y * 256 + tid;
  float sum = 0.f; int cnt = 0;
  for (int s = 0; s < 115; ++s)
    if (syv[s] == c) { sum += sx[(size_t)s * 1024 + d]; ++cnt; }
  out[2 + (size_t)c * 1024 + d] =
      0.5f * (sum / (float)(cnt > 0 ? cnt : 1)) + 0.25f * center[(size_t)c * 1024 + d];
}

__global__ __launch_bounds__(256)
void finalize_k(const float* __restrict__ bpre, const int* __restrict__ sy,
                const int* __restrict__ qy, float* __restrict__ out) {
  __shared__ float bls[23][115];
  __shared__ float dis[23][23];
  __shared__ int   syv[115];
  __shared__ float ccnt[23];
  __shared__ float lossq[23];
  __shared__ float accq[23];
  const int tid = threadIdx.x;
  if (tid < 115) syv[tid] = sy[tid];
  __syncthreads();
  if (tid < 23) {
    float mx = -3.4e38f;
    for (int s = 0; s < 115; ++s) mx = fmaxf(mx, bpre[tid * 115 + s]);
    float se = 0.f;
    for (int s = 0; s < 115; ++s) se += expf(bpre[tid * 115 + s] - mx);
    float lse = mx + logf(se);
    for (int s = 0; s < 115; ++s) bls[tid][s] = bpre[tid * 115 + s] - lse;
    int c = 0;
    for (int s = 0; s < 115; ++s) c += (syv[s] == tid);
    ccnt[tid] = (float)(c > 0 ? c : 1);
  }
  __syncthreads();
  for (int i = tid; i < 23 * 23; i += 256) {
    int qq = i / 23, c = i - qq * 23;
    float sum = 0.f;
    for (int s = 0; s < 115; ++s)
      if (syv[s] == c) sum += bls[qq][s];
    dis[qq][c] = sum / ccnt[c];
  }
  __syncthreads();
  if (tid < 23) {
    int qq = tid;
    float mx = -3.4e38f; int am = 0;
    for (int c = 0; c < 23; ++c) {
      float v = dis[qq][c];
      if (v > mx) { mx = v; am = c; }
    }
    float se = 0.f;
    for (int c = 0; c < 23; ++c) se += expf(dis[qq][c] - mx);
    float lse = mx + logf(se);
    int y = qy[qq];
    lossq[qq] = -(dis[qq][y] - lse);
    accq[qq] = (am == y) ? 1.f : 0.f;
  }
  __syncthreads();
  if (tid == 0) {
    float L = 0.f, A = 0.f;
    for (int qq = 0; qq < 23; ++qq) { L += lossq[qq]; A += accq[qq]; }
    out[0] = L;
    out[1] = A;
  }
}

// ---------------------------------------------------------------------------
extern "C" void kernel_launch(void* const* d_in, const int* in_sizes, int n_in,
                              void* d_out, int out_size, void* d_ws, size_t ws_size,
                              hipStream_t stream) {
  const float* sup_x  = (const float*)d_in[0];
  const int*   sup_ei = (const int*)d_in[1];
  const int*   sup_y  = (const int*)d_in[3];
  const float* q_x    = (const float*)d_in[4];
  const int*   q_ei   = (const int*)d_in[5];
  const int*   q_y    = (const int*)d_in[7];
  const float* center = (const float*)d_in[8];
  const float* cw1    = (const float*)d_in[9];
  const float* cb1    = (const float*)d_in[10];
  const float* cwr    = (const float*)d_in[11];
  const float* cbr    = (const float*)d_in[12];
  const float* l2w    = (const float*)d_in[13];
  const float* l2b    = (const float*)d_in[14];
  const float* mw     = (const float*)d_in[15];
  const float* mb     = (const float*)d_in[16];
  float* out = (float*)d_out;

  // ---- workspace carve-up (bytes, 256-aligned) ----
  char* base = (char*)d_ws;
  size_t off = 0;
  auto alloc = [&](size_t n) { char* p = base + off; off += (n + 255) & ~(size_t)255; return p; };
  _Float16* wbuf5 = (_Float16*)alloc(5 * WL * 2);
  _Float16* w1buf = (_Float16*)alloc(2048 * 2);
  float* h1   = (float*)alloc(138 * 1024 * 4);
  float* sxb  = (float*)alloc(138 * 1024 * 4);
  float* h2p  = (float*)alloc(138 * 1024 * 4);
  float* h2   = (float*)alloc(138 * 1024 * 4);
  float* feat = (float*)alloc(138 * 1024 * 4);
  float* bpre = (float*)alloc(23 * 115 * 4);

  const size_t R1_FULL = 138ull * 64 * 64 * 64 * 2;    //  72,351,744 (L2 out, all)
  const size_t R0_FULL = 115ull * 128 * 128 * 64 * 2;  // 241,172,480 (L1 out, 115)
  const size_t R0_23   = 23ull * 128 * 128 * 64 * 2;   //  48,234,496
  const size_t R1_SML  = 12ull * 64 * 64 * 64 * 2;
  const size_t R0_SML  = 12ull * 128 * 128 * 64 * 2;

  const int tier = (ws_size >= off + R1_FULL + R0_FULL + 4096) ? 0
                 : (ws_size >= off + R1_FULL + R0_23 + 4096)   ? 1 : 2;

  _Float16* region1 = (_Float16*)alloc(tier <= 1 ? R1_FULL : R1_SML);
  _Float16* region0 = (_Float16*)alloc(tier == 0 ? R0_FULL : (tier == 1 ? R0_23 : R0_SML));
  _Float16* l3out = region0;
  _Float16* l4out = region0 + (tier <= 1 ? 9043968u : 786432u);
  _Float16* l5out = region0 + (tier <= 1 ? 11304960u : 983040u);
  _Float16* wlin2 = region0;               // overlays, dead after conv chain
  _Float16* wmlp  = region0 + 1048576u;

  wtransform<<<728, 256, 0, stream>>>(cwr, cw1, wbuf5, w1buf);

  if (tier == 0) {
    // L1+L2 full support batch, then query; L3-L6 full batch.
    conv_l1<<<dim3(16, 16, 115), 256, 0, stream>>>(sup_x, region0, w1buf, cb1);
    conv_mfma<16, 16, false><<<dim3(8, 8, 115), 256, 0, stream>>>(
        region0, region1, wbuf5, cbr, 128, 128);
    conv_l1<<<dim3(16, 16, 23), 256, 0, stream>>>(q_x, region0, w1buf, cb1);
    conv_mfma<16, 16, false><<<dim3(8, 8, 23), 256, 0, stream>>>(
        region0, region1 + 115ull * 64 * 64 * 64, wbuf5, cbr, 128, 128);
    conv_mfma<16, 16, false><<<dim3(4, 4, 138), 256, 0, stream>>>(
        region1, l3out, wbuf5 + 1 * WL, cbr + 64, 64, 64);
    conv_mfma<16, 16, false><<<dim3(2, 2, 138), 256, 0, stream>>>(
        l3out, l4out, wbuf5 + 2 * WL, cbr + 128, 32, 32);
    conv_mfma<16, 16, false><<<dim3(1, 1, 138), 256, 0, stream>>>(
        l4out, l5out, wbuf5 + 3 * WL, cbr + 192, 16, 16);
    conv_mfma<8, 8, true><<<dim3(1, 1, 138), 256, 0, stream>>>(
        l5out, h1, wbuf5 + 4 * WL, cbr + 256, 8, 8);
  } else if (tier == 1) {
    for (int c = 0; c < 6; ++c) {
      const float* xin = (c < 5) ? (sup_x + (size_t)c * 23 * 3 * 65536) : q_x;
      conv_l1<<<dim3(16, 16, 23), 256, 0, stream>>>(xin, region0, w1buf, cb1);
      conv_mfma<16, 16, false><<<dim3(8, 8, 23), 256, 0, stream>>>(
          region0, region1 + (size_t)c * 23 * 64 * 64 * 64, wbuf5, cbr, 128, 128);
    }
    conv_mfma<16, 16, false><<<dim3(4, 4, 138), 256, 0, stream>>>(
        region1, l3out, wbuf5 + 1 * WL, cbr + 64, 64, 64);
    conv_mfma<16, 16, false><<<dim3(2, 2, 138), 256, 0, stream>>>(
        l3out, l4out, wbuf5 + 2 * WL, cbr + 128, 32, 32);
    conv_mfma<16, 16, false><<<dim3(1, 1, 138), 256, 0, stream>>>(
        l4out, l5out, wbuf5 + 3 * WL, cbr + 192, 16, 16);
    conv_mfma<8, 8, true><<<dim3(1, 1, 138), 256, 0, stream>>>(
        l5out, h1, wbuf5 + 4 * WL, cbr + 256, 8, 8);
  } else {
    auto run_chain = [&](const float* xin, int n, int gb) {
      conv_l1<<<dim3(16, 16, n), 256, 0, stream>>>(xin, region0, w1buf, cb1);
      conv_mfma<16, 16, false><<<dim3(8, 8, n), 256, 0, stream>>>(
          region0, region1, wbuf5, cbr, 128, 128);
      conv_mfma<16, 16, false><<<dim3(4, 4, n), 256, 0, stream>>>(
          region1, l3out, wbuf5 + 1 * WL, cbr + 64, 64, 64);
      conv_mfma<16, 16, false><<<dim3(2, 2, n), 256, 0, stream>>>(
          l3out, l4out, wbuf5 + 2 * WL, cbr + 128, 32, 32);
      conv_mfma<16, 16, false><<<dim3(1, 1, n), 256, 0, stream>>>(
          l4out, l5out, wbuf5 + 3 * WL, cbr + 192, 16, 16);
      conv_mfma<8, 8, true><<<dim3(1, 1, n), 256, 0, stream>>>(
          l5out, h1 + (size_t)gb * 1024, wbuf5 + 4 * WL, cbr + 256, 8, 8);
    };
    for (int i0 = 0; i0 < 115; i0 += 12)
      run_chain(sup_x + (size_t)i0 * 3 * 65536, (115 - i0 < 12) ? 115 - i0 : 12, i0);
    for (int i0 = 0; i0 < 23; i0 += 12)
      run_chain(q_x + (size_t)i0 * 3 * 65536, (23 - i0 < 12) ? 23 - i0 : 12, 115 + i0);
  }

  // ---- lin weight fragments (region0 now dead) ----
  wtransform_lin<<<4096, 256, 0, stream>>>(l2w, wlin2, 32);
  wtransform_lin<<<8192, 256, 0, stream>>>(mw, wmlp, 64);

  // ---- graph layers (support rows 0..114, query rows 115..137) ----
  edge_agg_mul<<<115, 256, 0, stream>>>(h1, sup_ei, 4096, sxb);
  edge_agg_mul<<<23, 256, 0, stream>>>(h1 + 115 * 1024, q_ei, 1024, sxb + 115 * 1024);
  gemm_mfma<1024><<<dim3(32, 9), 256, 0, stream>>>(sxb, nullptr, wlin2, l2b, h2p, 138);
  edge_agg_mul<<<115, 256, 0, stream>>>(h2p, sup_ei, 4096, h2);
  edge_agg_mul<<<23, 256, 0, stream>>>(h2p + 115 * 1024, q_ei, 1024, h2 + 115 * 1024);
  gemm_mfma<2048><<<dim3(32, 9), 256, 0, stream>>>(h1, h2, wmlp, mb, feat, 138);

  // ---- metric head ----
  rbf_pairs<<<(23 * 115 * 64 + 255) / 256, 256, 0, stream>>>(
      feat, feat + 115 * 1024, center, bpre);
  center_new_k<<<dim3(23, 4), 256, 0, stream>>>(feat, center, sup_y, out);
  finalize_k<<<1, 256, 0, stream>>>(bpre, sup_y, q_y, out);
}

// Round 11
// 661.403 us; speedup vs baseline: 1.2344x; 1.0493x over previous
//
#include <hip/hip_runtime.h>
#include <cstdint>
#include <cstddef>

// ===========================================================================
// FP16 MFMA pipeline (R18).
// R18 changes vs R17 (694us; R17's store-vectorization was NEUTRAL —
// conv_l1 stuck at ~165us, VALUBusy ~50% => the cost is the staging
// FRONT-END, per R17's falsifier):
//  (1) conv_l1 core/ring staging split: halo [3][18][18] = aligned 16x16
//      core + 68-elem ring per channel. Core (tid<192): ic/ry/chunk from
//      SHIFTS only, no bounds check, one 64B-aligned coalesced float4 load
//      (x0 is 16-aligned). Ring (tid<204): one predicated scalar load,
//      single /68. Loads/thread 4 -> <=2, staging divisions 8 -> 1.
//      T14 ordering kept: both loads issue before either LDS write.
// ===========================================================================

typedef _Float16 f16x8 __attribute__((ext_vector_type(8)));
typedef __attribute__((ext_vector_type(4))) float f32x4;

#define WL 36864  // fp16 elems per transformed conv layer: 9 taps * 8 * 512

// ---------------------------------------------------------------------------
// Conv weight transform: cw_rest [5][64][64][3][3] ->
//   wbuf5 [5][tap9][cc2][nt4][64][8] fp16 ; cw1 -> w1buf [nt4][64][8] (K=27 pad 32)
// ---------------------------------------------------------------------------
__global__ __launch_bounds__(256)
void wtransform(const float* __restrict__ cwr, const float* __restrict__ cw1,
                _Float16* __restrict__ wbuf5, _Float16* __restrict__ w1buf) {
  int i = blockIdx.x * 256 + threadIdx.x;
  if (i < 184320) {
    int layer = i / 36864; int rem = i - layer * 36864;
    int tap = rem / 4096;  int r2 = rem - tap * 4096;
    int cc = r2 / 2048;    int r3 = r2 - cc * 2048;
    int nt = r3 / 512;     int r4 = r3 - nt * 512;
    int lane = r4 / 8;     int j = r4 - lane * 8;
    int ic = cc * 32 + (lane >> 4) * 8 + j;
    int oc = nt * 16 + (lane & 15);
    float w = cwr[(((size_t)layer * 64 + oc) * 64 + ic) * 9 + tap];
    wbuf5[(size_t)layer * 36864 + tap * 4096 + (cc * 4 + nt) * 512 + lane * 8 + j] =
        (_Float16)w;
  } else if (i < 184320 + 2048) {
    int e = i - 184320;
    int nt = e / 512; int r4 = e - nt * 512;
    int lane = r4 / 8; int j = r4 - lane * 8;
    int k = (lane >> 4) * 8 + j;
    float w = 0.f;
    if (k < 27) {
      int tap = k / 3, ic = k - tap * 3;
      int oc = nt * 16 + (lane & 15);
      w = cw1[((size_t)oc * 3 + ic) * 9 + tap];
    }
    w1buf[nt * 512 + lane * 8 + j] = (_Float16)w;
  }
}

// ---------------------------------------------------------------------------
// Lin weight transform: W [K,1024] -> frag [K/32][nt64][64][8] fp16.
// ---------------------------------------------------------------------------
__global__ __launch_bounds__(256)
void wtransform_lin(const float* __restrict__ w, _Float16* __restrict__ frag,
                    int KS) {
  int i = blockIdx.x * 256 + threadIdx.x;
  int total = KS * 64 * 512;
  if (i >= total) return;
  int ks = i / (64 * 512); int rem = i - ks * (64 * 512);
  int nt = rem / 512;      int r = rem - nt * 512;
  int lane = r / 8;        int j = r - lane * 8;
  int k = ks * 32 + (lane >> 4) * 8 + j;
  int n = nt * 16 + (lane & 15);
  frag[((size_t)ks * 64 + nt) * 512 + lane * 8 + j] = (_Float16)w[(size_t)k * 1024 + n];
}

// ---------------------------------------------------------------------------
// FP16 MFMA gemm: out[m,n] = sum_k A[m,k] W[k,n] + bias[n]; A fp32 rows.
// 32-col blocks, grid (32, ceil(M/16)) = 288 blocks.
// ---------------------------------------------------------------------------
template<int KTOT>
__global__ __launch_bounds__(256)
void gemm_mfma(const float* __restrict__ A1, const float* __restrict__ A2,
               const _Float16* __restrict__ frag,
               const float* __restrict__ bias, float* __restrict__ out, int M) {
  __shared__ f32x4 s_red[4][2][64];  // 8KB
  const int tid = threadIdx.x;
  const int wave = tid >> 6, lane = tid & 63;
  const int q = lane >> 4, ml = lane & 15;
  const int m0 = blockIdx.y * 16;
  const int nb = blockIdx.x;           // 32-col block
  int row = m0 + ml; if (row >= M) row = M - 1;

  f32x4 acc[2];
#pragma unroll
  for (int nt = 0; nt < 2; ++nt) acc[nt] = (f32x4){0.f, 0.f, 0.f, 0.f};

  constexpr int KSW = KTOT / 128;
  const int ksBase = wave * KSW;
#pragma unroll 2
  for (int s = 0; s < KSW; ++s) {
    int ks = ksBase + s;
    int k0 = ks * 32 + q * 8;
    const float* ap;
    if constexpr (KTOT == 2048) {
      ap = (k0 >= 1024) ? (A2 + (size_t)row * 1024 + (k0 - 1024))
                        : (A1 + (size_t)row * 1024 + k0);
    } else {
      ap = A1 + (size_t)row * 1024 + k0;
    }
    float4 va = *(const float4*)ap;
    float4 vb = *(const float4*)(ap + 4);
    f16x8 av;
    av[0] = (_Float16)va.x; av[1] = (_Float16)va.y;
    av[2] = (_Float16)va.z; av[3] = (_Float16)va.w;
    av[4] = (_Float16)vb.x; av[5] = (_Float16)vb.y;
    av[6] = (_Float16)vb.z; av[7] = (_Float16)vb.w;
    const _Float16* fb = frag + ((size_t)ks * 64 + nb * 2) * 512 + lane * 8;
#pragma unroll
    for (int nt = 0; nt < 2; ++nt) {
      f16x8 bv = *(const f16x8*)(fb + nt * 512);
      acc[nt] = __builtin_amdgcn_mfma_f32_16x16x32_f16(av, bv, acc[nt], 0, 0, 0);
    }
  }
#pragma unroll
  for (int nt = 0; nt < 2; ++nt) s_red[wave][nt][lane] = acc[nt];
  __syncthreads();
  if (wave < 2) {
    int nt = wave;
    f32x4 sum = s_red[0][nt][lane];
#pragma unroll
    for (int w2 = 1; w2 < 4; ++w2) {
      f32x4 p = s_red[w2][nt][lane];
      sum[0] += p[0]; sum[1] += p[1]; sum[2] += p[2]; sum[3] += p[3];
    }
    int n = nb * 32 + nt * 16 + ml;
    float bv = bias[n];
#pragma unroll
    for (int r = 0; r < 4; ++r) {
      int m = m0 + q * 4 + r;
      if (m < M) out[(size_t)m * 1024 + n] = sum[r] + bv;
    }
  }
}

// ---------------------------------------------------------------------------
// conv3x3(SAME)+bias+relu+maxpool2, IC=OC=64, fp16 MFMA implicit GEMM.
// 16x16 tile, 47KB stride-72 patch (conflict-free), 3 blocks/CU.
// Two-phase staging (T14) + one-tap-ahead weight prefetch.
// fp16-out epilogue via LDS transpose (reusing dead s_patch) ->
// 2 coalesced uint4 stores per thread.
// ---------------------------------------------------------------------------
template<int TCX, int TCY, bool FP32OUT>
__global__ __launch_bounds__(256, 3)
void conv_mfma(const _Float16* __restrict__ act_in,
               void* __restrict__ act_out,
               const _Float16* __restrict__ wbuf,   // [9][cc2][nt4][64][8]
               const float* __restrict__ bias,
               int IH, int IW) {
  constexpr int PX = TCX + 2, PY = TCY + 2;
  constexpr int MT = (TCX * TCY) / 64;
  constexpr int TOT = PY * PX * 8;
  constexpr int ITERS = (TOT + 255) / 256;
  __shared__ __align__(16) _Float16 s_patch[PY * PX * 72];

  const int tid = threadIdx.x;
  const int wave = tid >> 6, lane = tid & 63;
  const int q = lane >> 4, ml = lane & 15;
  const int x0 = blockIdx.x * TCX, y0 = blockIdx.y * TCY;
  const int img = blockIdx.z;

  // ---- stage phase A: issue ALL loads into registers (latency overlapped)
  uint4 rbuf[ITERS];
#pragma unroll
  for (int i = 0; i < ITERS; ++i) {
    int u = tid + i * 256;
    uint4 v = {0u, 0u, 0u, 0u};
    if (u < TOT) {
      int pos = u >> 3, sub = u & 7;
      int py = pos / PX, px = pos - py * PX;
      int gy = y0 - 1 + py, gx = x0 - 1 + px;
      if ((unsigned)gy < (unsigned)IH && (unsigned)gx < (unsigned)IW)
        v = *(const uint4*)(act_in + (((size_t)img * IH + gy) * IW + gx) * 64 + sub * 8);
    }
    rbuf[i] = v;
  }
  // ---- stage phase B: write to LDS (single drain)
#pragma unroll
  for (int i = 0; i < ITERS; ++i) {
    int u = tid + i * 256;
    if (u < TOT) {
      int pos = u >> 3, sub = u & 7;
      *(uint4*)(s_patch + pos * 72 + sub * 8) = rbuf[i];
    }
  }

  // prefetch tap 0 weights (both cc chunks, 8 fragments)
  const _Float16* wl = wbuf + lane * 8;
  f16x8 bw[8], bn[8];
#pragma unroll
  for (int f = 0; f < 8; ++f) bw[f] = *(const f16x8*)(wl + f * 512);

  __syncthreads();

  f32x4 acc[MT][4];
#pragma unroll
  for (int mt = 0; mt < MT; ++mt)
#pragma unroll
    for (int nt = 0; nt < 4; ++nt)
      acc[mt][nt] = (f32x4){0.f, 0.f, 0.f, 0.f};

  int pxv[MT], pyv[MT];
#pragma unroll
  for (int mt = 0; mt < MT; ++mt) {
    int p = (wave * MT + mt) * 16 + ml;
    pxv[mt] = p % TCX;
    pyv[mt] = p / TCX;
  }

#pragma unroll 1
  for (int tap = 0; tap < 9; ++tap) {
    if (tap < 8) {
      const _Float16* np = wl + (tap + 1) * 4096;
#pragma unroll
      for (int f = 0; f < 8; ++f) bn[f] = *(const f16x8*)(np + f * 512);
    }
    const int dy = tap / 3, dx = tap - dy * 3;
#pragma unroll
    for (int cc = 0; cc < 2; ++cc) {
#pragma unroll
      for (int mt = 0; mt < MT; ++mt) {
        const _Float16* ap =
            s_patch + ((pyv[mt] + dy) * PX + (pxv[mt] + dx)) * 72 + cc * 32 + q * 8;
        f16x8 av = *(const f16x8*)ap;
#pragma unroll
        for (int nt = 0; nt < 4; ++nt)
          acc[mt][nt] = __builtin_amdgcn_mfma_f32_16x16x32_f16(av, bw[cc * 4 + nt],
                                                               acc[mt][nt], 0, 0, 0);
      }
    }
#pragma unroll
    for (int f = 0; f < 8; ++f) bw[f] = bn[f];
  }

  // ---- bias+relu+2x2 maxpool + store ----
  const int OH = IH >> 1, OW = IW >> 1;
  if constexpr (TCX == 16 && !FP32OUT) {
    // LDS-transpose epilogue: pooled [8y][8x][64oc] staged at stride 72,
    // then 2 coalesced uint4 stores per thread.
    _Float16* s_out = s_patch;          // s_patch dead after tap loop
    __syncthreads();                    // all waves done reading s_patch
#pragma unroll
    for (int nt = 0; nt < 4; ++nt) {
      int oc = nt * 16 + ml;
      float bvs = bias[oc];
#pragma unroll
      for (int mh = 0; mh < MT / 2; ++mh)
#pragma unroll
        for (int rh = 0; rh < 2; ++rh) {
          float a0 = fmaxf(acc[2 * mh][nt][2 * rh] + bvs, 0.f);
          float a1 = fmaxf(acc[2 * mh][nt][2 * rh + 1] + bvs, 0.f);
          float a2 = fmaxf(acc[2 * mh + 1][nt][2 * rh] + bvs, 0.f);
          float a3 = fmaxf(acc[2 * mh + 1][nt][2 * rh + 1] + bvs, 0.f);
          float m = fmaxf(fmaxf(a0, a1), fmaxf(a2, a3));
          int lp = (wave * (MT / 2) + mh) * 8 + q * 2 + rh;   // local pooled pos
          s_out[lp * 72 + oc] = (_Float16)m;
        }
    }
    __syncthreads();
#pragma unroll
    for (int i = 0; i < 2; ++i) {
      int u = tid + i * 256;            // 512 uint4s total
      int pos = u >> 3, sub = u & 7;
      uint4 v = *(const uint4*)(s_out + pos * 72 + sub * 8);
      int gy = (y0 >> 1) + (pos >> 3);
      int gx = (x0 >> 1) + (pos & 7);
      *(uint4*)((_Float16*)act_out + (((size_t)img * OH + gy) * OW + gx) * 64 + sub * 8) = v;
    }
  } else {
#pragma unroll
    for (int nt = 0; nt < 4; ++nt) {
      int oc = nt * 16 + ml;
      float bvs = bias[oc];
      if constexpr (TCX == 16) {
#pragma unroll
        for (int mh = 0; mh < MT / 2; ++mh)
#pragma unroll
          for (int rh = 0; rh < 2; ++rh) {
            float a0 = fmaxf(acc[2 * mh][nt][2 * rh] + bvs, 0.f);
            float a1 = fmaxf(acc[2 * mh][nt][2 * rh + 1] + bvs, 0.f);
            float a2 = fmaxf(acc[2 * mh + 1][nt][2 * rh] + bvs, 0.f);
            float a3 = fmaxf(acc[2 * mh + 1][nt][2 * rh + 1] + bvs, 0.f);
            float m = fmaxf(fmaxf(a0, a1), fmaxf(a2, a3));
            int gy = (y0 >> 1) + wave * (MT / 2) + mh;
            int gx = (x0 >> 1) + q * 2 + rh;
            ((float*)act_out)[(((size_t)img * 64 + oc) * OH + gy) * OW + gx] = m;
          }
      } else {  // TCX==8, MT==1: y-pool across q>>1 via shfl_xor(32)
        float m01 = fmaxf(fmaxf(acc[0][nt][0] + bvs, 0.f), fmaxf(acc[0][nt][1] + bvs, 0.f));
        float m23 = fmaxf(fmaxf(acc[0][nt][2] + bvs, 0.f), fmaxf(acc[0][nt][3] + bvs, 0.f));
        float p0 = fmaxf(m01, __shfl_xor(m01, 32));
        float p1 = fmaxf(m23, __shfl_xor(m23, 32));
        if ((lane & 32) == 0) {
          int gy = (y0 >> 1) + wave;
          int gx0 = (x0 >> 1) + (q & 1) * 2;
          if (FP32OUT) {
            float* o = (float*)act_out + (((size_t)img * 64 + oc) * OH + gy) * OW + gx0;
            o[0] = p0; o[1] = p1;
          } else {
            _Float16* o = (_Float16*)act_out;
            o[(((size_t)img * OH + gy) * OW + gx0) * 64 + oc] = (_Float16)p0;
            o[(((size_t)img * OH + gy) * OW + gx0 + 1) * 64 + oc] = (_Float16)p1;
          }
        }
      }
    }
  }
}

// ---------------------------------------------------------------------------
// Layer 1: IC=3, K=27 (pad 32), planar fp32 input. Tile 16x16 -> pooled 8x8.
// R18: core/ring staging — core (tid<192) = one aligned coalesced float4,
// shift-only indexing, no bounds check; ring (tid<204) = one predicated
// scalar load. Per-lane loop-invariant im2col offsets; LDS-transpose
// epilogue -> 2 coalesced uint4 stores per thread.
// ---------------------------------------------------------------------------
__global__ __launch_bounds__(256, 4)
void conv_l1(const float* __restrict__ in, _Float16* __restrict__ act_out,
             const _Float16* __restrict__ w1buf, const float* __restrict__ bias) {
  __shared__ __align__(16) _Float16 s_rawh[1280];  // [3][18][18]=972 + zero pad
  __shared__ __align__(16) _Float16 s_out[64 * 72]; // pooled [64 pos][72] 9.2KB

  const int tid = threadIdx.x;
  const int wave = tid >> 6, lane = tid & 63;
  const int q = lane >> 4, ml = lane & 15;
  const int x0 = blockIdx.x * 16, y0 = blockIdx.y * 16;
  const int img = blockIdx.z;

  // zero pad region [972, 1280) absorbs k>=27 fragment reads
  if (tid < 308) s_rawh[972 + tid] = (_Float16)0.f;

  // ---- stage phase A: issue core + ring loads (latency overlapped) ----
  // core: interior 16x16 of each channel -> one aligned float4, shifts only
  const int cic = tid >> 6, crem = tid & 63;
  const int cry = crem >> 2, crxc = crem & 3;
  float4 cv = {0.f, 0.f, 0.f, 0.f};
  if (tid < 192)
    cv = *(const float4*)(in + ((size_t)img * 3 + cic) * 65536 +
                          (size_t)(y0 + cry) * 256 + x0 + crxc * 4);
  // ring: 68 border elems per channel (top row, bottom row, two cols)
  float rv = 0.f;
  int ric = 0, ryy = 0, rxx = 0;
  if (tid < 204) {
    ric = tid / 68;
    int r = tid - ric * 68;
    if (r < 36) { ryy = (r < 18) ? 0 : 17; rxx = (r < 18) ? r : r - 18; }
    else        { rxx = (r < 52) ? 0 : 17; ryy = 1 + ((r < 52) ? r - 36 : r - 52); }
    int gy = y0 - 1 + ryy, gx = x0 - 1 + rxx;
    if ((unsigned)gy < 256u && (unsigned)gx < 256u)
      rv = in[((size_t)img * 3 + ric) * 65536 + (size_t)gy * 256 + gx];
  }
  // ---- stage phase B: convert + write to LDS ----
  if (tid < 192) {
    _Float16* d = s_rawh + cic * 324 + (cry + 1) * 18 + crxc * 4 + 1;
    d[0] = (_Float16)cv.x; d[1] = (_Float16)cv.y;
    d[2] = (_Float16)cv.z; d[3] = (_Float16)cv.w;
  }
  if (tid < 204) s_rawh[ric * 324 + ryy * 18 + rxx] = (_Float16)rv;

  // per-lane loop-invariant im2col offsets (halfword units)
  int offs[8];
#pragma unroll
  for (int j = 0; j < 8; ++j) {
    int k = q * 8 + j;
    int tap = k / 3, ic = k - tap * 3;
    int ddy = tap / 3, ddx = tap - ddy * 3;
    offs[j] = (k < 27) ? (ic * 324 + ddy * 18 + ddx + ml) : 972;
  }

  f16x8 bv[4];
#pragma unroll
  for (int nt = 0; nt < 4; ++nt)
    bv[nt] = *(const f16x8*)(w1buf + nt * 512 + lane * 8);

  __syncthreads();

  f32x4 acc[4][4];
#pragma unroll
  for (int t4 = 0; t4 < 4; ++t4)
#pragma unroll
    for (int nt = 0; nt < 4; ++nt)
      acc[t4][nt] = (f32x4){0.f, 0.f, 0.f, 0.f};

#pragma unroll
  for (int t4 = 0; t4 < 4; ++t4) {
    const int tb = (wave * 4 + t4) * 18;   // t = y row within 16x16 tile
    f16x8 av;
#pragma unroll
    for (int j = 0; j < 8; ++j) av[j] = s_rawh[offs[j] + tb];
#pragma unroll
    for (int nt = 0; nt < 4; ++nt)
      acc[t4][nt] = __builtin_amdgcn_mfma_f32_16x16x32_f16(av, bv[nt], acc[t4][nt], 0, 0, 0);
  }

  // ---- LDS-transpose epilogue ----
#pragma unroll
  for (int nt = 0; nt < 4; ++nt) {
    int oc = nt * 16 + ml;
    float bvs = bias[oc];
#pragma unroll
    for (int mh = 0; mh < 2; ++mh)
#pragma unroll
      for (int rh = 0; rh < 2; ++rh) {
        float a0 = fmaxf(acc[2 * mh][nt][2 * rh] + bvs, 0.f);
        float a1 = fmaxf(acc[2 * mh][nt][2 * rh + 1] + bvs, 0.f);
        float a2 = fmaxf(acc[2 * mh + 1][nt][2 * rh] + bvs, 0.f);
        float a3 = fmaxf(acc[2 * mh + 1][nt][2 * rh + 1] + bvs, 0.f);
        float m = fmaxf(fmaxf(a0, a1), fmaxf(a2, a3));
        int lp = (wave * 2 + mh) * 8 + q * 2 + rh;
        s_out[lp * 72 + oc] = (_Float16)m;
      }
  }
  __syncthreads();
#pragma unroll
  for (int i = 0; i < 2; ++i) {
    int u = tid + i * 256;
    int pos = u >> 3, sub = u & 7;
    uint4 v = *(const uint4*)(s_out + pos * 72 + sub * 8);
    int gy = blockIdx.y * 8 + (pos >> 3);
    int gx = blockIdx.x * 8 + (pos & 7);
    *(uint4*)(act_out + (((size_t)img * 128 + gy) * 128 + gx) * 64 + sub * 8) = v;
  }
}

// ---------------------------------------------------------------------------
// Graph aggregation (two-phase) + metric head (unchanged).
// ---------------------------------------------------------------------------
__global__ __launch_bounds__(256)
void edge_agg_mul(const float* __restrict__ h, const int* __restrict__ ei,
                  int E, float* __restrict__ out) {
  __shared__ int list[1024];
  __shared__ int cnt;
  const int n = blockIdx.x;
  const int tid = threadIdx.x;
  if (tid == 0) cnt = 0;
  __syncthreads();
  for (int e = tid; e < E; e += 256) {
    if (ei[E + e] == n) {
      int p = atomicAdd(&cnt, 1);
      list[p] = ei[e];
    }
  }
  __syncthreads();
  const int c = cnt;
  float ax = 0.f, ay = 0.f, az = 0.f, aw = 0.f;
#pragma unroll 4
  for (int i = 0; i < c; ++i) {
    const float4 v = ((const float4*)(h + (size_t)list[i] * 1024))[tid];
    ax += v.x; ay += v.y; az += v.z; aw += v.w;
  }
  float inv = 1.f / (float)(c > 0 ? c : 1);
  const float4 hv = ((const float4*)(h + (size_t)n * 1024))[tid];
  float4 o;
  o.x = ax * inv * hv.x; o.y = ay * inv * hv.y;
  o.z = az * inv * hv.z; o.w = aw * inv * hv.w;
  ((float4*)(out + (size_t)n * 1024))[tid] = o;
}

__global__ __launch_bounds__(256)
void rbf_pairs(const float* __restrict__ sx, const float* __restrict__ qx,
               const float* __restrict__ center, float* __restrict__ bpre) {
  int gid = blockIdx.x * 256 + threadIdx.x;
  int wid = gid >> 6;
  int lane = gid & 63;
  if (wid >= 23 * 115) return;
  int qq = wid / 115, s = wid - qq * 115;
  const float* sr = sx + (size_t)s * 1024;
  const float* qr = qx + (size_t)qq * 1024;
  const float* cr = center + (size_t)(s / 5) * 1024;
  float S1 = 0.f, S2 = 0.f, S3 = 0.f;
  for (int d = lane; d < 1024; d += 64) {
    float sv = sr[d], qv = qr[d];
    float df = sv - qv;
    float a = expf(-df * df);
    S1 += a;
    S2 += expf(a);
    float sc = 0.25f * cr[d] + 0.5f * sv;
    float d2 = sc - qv;
    S3 += expf(-d2 * d2);
  }
#pragma unroll
  for (int o = 32; o > 0; o >>= 1) {
    S1 += __shfl_down(S1, o);
    S2 += __shfl_down(S2, o);
    S3 += __shfl_down(S3, o);
  }
  if (lane == 0) bpre[wid] = S3 + S1 - 1024.f * logf(S2);
}

__global__ __launch_bounds__(256)
void center_new_k(const float* __restrict__ sx, const float* __restrict__ center,
                  const int* __restrict__ sy, float* __restrict__ out) {
  __shared__ int syv[115];
  int tid = threadIdx.x;
  if (tid < 115) syv[tid] = sy[tid];
  __syncthreads();
  int c = blockIdx.x;
  int d = blockIdx.y * 256 + tid;
  float sum = 0.f; int cnt = 0;
  for (int s = 0; s < 115; ++s)
    if (syv[s] == c) { sum += sx[(size_t)s * 1024 + d]; ++cnt; }
  out[2 + (size_t)c * 1024 + d] =
      0.5f * (sum / (float)(cnt > 0 ? cnt : 1)) + 0.25f * center[(size_t)c * 1024 + d];
}

__global__ __launch_bounds__(256)
void finalize_k(const float* __restrict__ bpre, const int* __restrict__ sy,
                const int* __restrict__ qy, float* __restrict__ out) {
  __shared__ float bls[23][115];
  __shared__ float dis[23][23];
  __shared__ int   syv[115];
  __shared__ float ccnt[23];
  __shared__ float lossq[23];
  __shared__ float accq[23];
  const int tid = threadIdx.x;
  if (tid < 115) syv[tid] = sy[tid];
  __syncthreads();
  if (tid < 23) {
    float mx = -3.4e38f;
    for (int s = 0; s < 115; ++s) mx = fmaxf(mx, bpre[tid * 115 + s]);
    float se = 0.f;
    for (int s = 0; s < 115; ++s) se += expf(bpre[tid * 115 + s] - mx);
    float lse = mx + logf(se);
    for (int s = 0; s < 115; ++s) bls[tid][s] = bpre[tid * 115 + s] - lse;
    int c = 0;
    for (int s = 0; s < 115; ++s) c += (syv[s] == tid);
    ccnt[tid] = (float)(c > 0 ? c : 1);
  }
  __syncthreads();
  for (int i = tid; i < 23 * 23; i += 256) {
    int qq = i / 23, c = i - qq * 23;
    float sum = 0.f;
    for (int s = 0; s < 115; ++s)
      if (syv[s] == c) sum += bls[qq][s];
    dis[qq][c] = sum / ccnt[c];
  }
  __syncthreads();
  if (tid < 23) {
    int qq = tid;
    float mx = -3.4e38f; int am = 0;
    for (int c = 0; c < 23; ++c) {
      float v = dis[qq][c];
      if (v > mx) { mx = v; am = c; }
    }
    float se = 0.f;
    for (int c = 0; c < 23; ++c) se += expf(dis[qq][c] - mx);
    float lse = mx + logf(se);
    int y = qy[qq];
    lossq[qq] = -(dis[qq][y] - lse);
    accq[qq] = (am == y) ? 1.f : 0.f;
  }
  __syncthreads();
  if (tid == 0) {
    float L = 0.f, A = 0.f;
    for (int qq = 0; qq < 23; ++qq) { L += lossq[qq]; A += accq[qq]; }
    out[0] = L;
    out[1] = A;
  }
}

// ---------------------------------------------------------------------------
extern "C" void kernel_launch(void* const* d_in, const int* in_sizes, int n_in,
                              void* d_out, int out_size, void* d_ws, size_t ws_size,
                              hipStream_t stream) {
  const float* sup_x  = (const float*)d_in[0];
  const int*   sup_ei = (const int*)d_in[1];
  const int*   sup_y  = (const int*)d_in[3];
  const float* q_x    = (const float*)d_in[4];
  const int*   q_ei   = (const int*)d_in[5];
  const int*   q_y    = (const int*)d_in[7];
  const float* center = (const float*)d_in[8];
  const float* cw1    = (const float*)d_in[9];
  const float* cb1    = (const float*)d_in[10];
  const float* cwr    = (const float*)d_in[11];
  const float* cbr    = (const float*)d_in[12];
  const float* l2w    = (const float*)d_in[13];
  const float* l2b    = (const float*)d_in[14];
  const float* mw     = (const float*)d_in[15];
  const float* mb     = (const float*)d_in[16];
  float* out = (float*)d_out;

  // ---- workspace carve-up (bytes, 256-aligned) ----
  char* base = (char*)d_ws;
  size_t off = 0;
  auto alloc = [&](size_t n) { char* p = base + off; off += (n + 255) & ~(size_t)255; return p; };
  _Float16* wbuf5 = (_Float16*)alloc(5 * WL * 2);
  _Float16* w1buf = (_Float16*)alloc(2048 * 2);
  float* h1   = (float*)alloc(138 * 1024 * 4);
  float* sxb  = (float*)alloc(138 * 1024 * 4);
  float* h2p  = (float*)alloc(138 * 1024 * 4);
  float* h2   = (float*)alloc(138 * 1024 * 4);
  float* feat = (float*)alloc(138 * 1024 * 4);
  float* bpre = (float*)alloc(23 * 115 * 4);

  const size_t R1_FULL = 138ull * 64 * 64 * 64 * 2;    //  72,351,744 (L2 out, all)
  const size_t R0_FULL = 115ull * 128 * 128 * 64 * 2;  // 241,172,480 (L1 out, 115)
  const size_t R0_23   = 23ull * 128 * 128 * 64 * 2;   //  48,234,496
  const size_t R1_SML  = 12ull * 64 * 64 * 64 * 2;
  const size_t R0_SML  = 12ull * 128 * 128 * 64 * 2;

  const int tier = (ws_size >= off + R1_FULL + R0_FULL + 4096) ? 0
                 : (ws_size >= off + R1_FULL + R0_23 + 4096)   ? 1 : 2;

  _Float16* region1 = (_Float16*)alloc(tier <= 1 ? R1_FULL : R1_SML);
  _Float16* region0 = (_Float16*)alloc(tier == 0 ? R0_FULL : (tier == 1 ? R0_23 : R0_SML));
  _Float16* l3out = region0;
  _Float16* l4out = region0 + (tier <= 1 ? 9043968u : 786432u);
  _Float16* l5out = region0 + (tier <= 1 ? 11304960u : 983040u);
  _Float16* wlin2 = region0;               // overlays, dead after conv chain
  _Float16* wmlp  = region0 + 1048576u;

  wtransform<<<728, 256, 0, stream>>>(cwr, cw1, wbuf5, w1buf);

  if (tier == 0) {
    // L1+L2 full support batch, then query; L3-L6 full batch.
    conv_l1<<<dim3(16, 16, 115), 256, 0, stream>>>(sup_x, region0, w1buf, cb1);
    conv_mfma<16, 16, false><<<dim3(8, 8, 115), 256, 0, stream>>>(
        region0, region1, wbuf5, cbr, 128, 128);
    conv_l1<<<dim3(16, 16, 23), 256, 0, stream>>>(q_x, region0, w1buf, cb1);
    conv_mfma<16, 16, false><<<dim3(8, 8, 23), 256, 0, stream>>>(
        region0, region1 + 115ull * 64 * 64 * 64, wbuf5, cbr, 128, 128);
    conv_mfma<16, 16, false><<<dim3(4, 4, 138), 256, 0, stream>>>(
        region1, l3out, wbuf5 + 1 * WL, cbr + 64, 64, 64);
    conv_mfma<16, 16, false><<<dim3(2, 2, 138), 256, 0, stream>>>(
        l3out, l4out, wbuf5 + 2 * WL, cbr + 128, 32, 32);
    conv_mfma<16, 16, false><<<dim3(1, 1, 138), 256, 0, stream>>>(
        l4out, l5out, wbuf5 + 3 * WL, cbr + 192, 16, 16);
    conv_mfma<8, 8, true><<<dim3(1, 1, 138), 256, 0, stream>>>(
        l5out, h1, wbuf5 + 4 * WL, cbr + 256, 8, 8);
  } else if (tier == 1) {
    for (int c = 0; c < 6; ++c) {
      const float* xin = (c < 5) ? (sup_x + (size_t)c * 23 * 3 * 65536) : q_x;
      conv_l1<<<dim3(16, 16, 23), 256, 0, stream>>>(xin, region0, w1buf, cb1);
      conv_mfma<16, 16, false><<<dim3(8, 8, 23), 256, 0, stream>>>(
          region0, region1 + (size_t)c * 23 * 64 * 64 * 64, wbuf5, cbr, 128, 128);
    }
    conv_mfma<16, 16, false><<<dim3(4, 4, 138), 256, 0, stream>>>(
        region1, l3out, wbuf5 + 1 * WL, cbr + 64, 64, 64);
    conv_mfma<16, 16, false><<<dim3(2, 2, 138), 256, 0, stream>>>(
        l3out, l4out, wbuf5 + 2 * WL, cbr + 128, 32, 32);
    conv_mfma<16, 16, false><<<dim3(1, 1, 138), 256, 0, stream>>>(
        l4out, l5out, wbuf5 + 3 * WL, cbr + 192, 16, 16);
    conv_mfma<8, 8, true><<<dim3(1, 1, 138), 256, 0, stream>>>(
        l5out, h1, wbuf5 + 4 * WL, cbr + 256, 8, 8);
  } else {
    auto run_chain = [&](const float* xin, int n, int gb) {
      conv_l1<<<dim3(16, 16, n), 256, 0, stream>>>(xin, region0, w1buf, cb1);
      conv_mfma<16, 16, false><<<dim3(8, 8, n), 256, 0, stream>>>(
          region0, region1, wbuf5, cbr, 128, 128);
      conv_mfma<16, 16, false><<<dim3(4, 4, n), 256, 0, stream>>>(
          region1, l3out, wbuf5 + 1 * WL, cbr + 64, 64, 64);
      conv_mfma<16, 16, false><<<dim3(2, 2, n), 256, 0, stream>>>(
          l3out, l4out, wbuf5 + 2 * WL, cbr + 128, 32, 32);
      conv_mfma<16, 16, false><<<dim3(1, 1, n), 256, 0, stream>>>(
          l4out, l5out, wbuf5 + 3 * WL, cbr + 192, 16, 16);
      conv_mfma<8, 8, true><<<dim3(1, 1, n), 256, 0, stream>>>(
          l5out, h1 + (size_t)gb * 1024, wbuf5 + 4 * WL, cbr + 256, 8, 8);
    };
    for (int i0 = 0; i0 < 115; i0 += 12)
      run_chain(sup_x + (size_t)i0 * 3 * 65536, (115 - i0 < 12) ? 115 - i0 : 12, i0);
    for (int i0 = 0; i0 < 23; i0 += 12)
      run_chain(q_x + (size_t)i0 * 3 * 65536, (23 - i0 < 12) ? 23 - i0 : 12, 115 + i0);
  }

  // ---- lin weight fragments (region0 now dead) ----
  wtransform_lin<<<4096, 256, 0, stream>>>(l2w, wlin2, 32);
  wtransform_lin<<<8192, 256, 0, stream>>>(mw, wmlp, 64);

  // ---- graph layers (support rows 0..114, query rows 115..137) ----
  edge_agg_mul<<<115, 256, 0, stream>>>(h1, sup_ei, 4096, sxb);
  edge_agg_mul<<<23, 256, 0, stream>>>(h1 + 115 * 1024, q_ei, 1024, sxb + 115 * 1024);
  gemm_mfma<1024><<<dim3(32, 9), 256, 0, stream>>>(sxb, nullptr, wlin2, l2b, h2p, 138);
  edge_agg_mul<<<115, 256, 0, stream>>>(h2p, sup_ei, 4096, h2);
  edge_agg_mul<<<23, 256, 0, stream>>>(h2p + 115 * 1024, q_ei, 1024, h2 + 115 * 1024);
  gemm_mfma<2048><<<dim3(32, 9), 256, 0, stream>>>(h1, h2, wmlp, mb, feat, 138);

  // ---- metric head ----
  rbf_pairs<<<(23 * 115 * 64 + 255) / 256, 256, 0, stream>>>(
      feat, feat + 115 * 1024, center, bpre);
  center_new_k<<<dim3(23, 4), 256, 0, stream>>>(feat, center, sup_y, out);
  finalize_k<<<1, 256, 0, stream>>>(bpre, sup_y, q_y, out);
}